// Round 2
// baseline (878.122 us; speedup 1.0000x reference)
//
#include <hip/hip_runtime.h>

typedef unsigned short u16;
typedef __bf16 bf16x8 __attribute__((ext_vector_type(8)));
typedef float f32x4 __attribute__((ext_vector_type(4)));
typedef unsigned short u16x8 __attribute__((ext_vector_type(8)));
typedef unsigned short u16x4 __attribute__((ext_vector_type(4)));
typedef float f4 __attribute__((ext_vector_type(4)));

__device__ __forceinline__ float bf2f(u16 u) {
    union { unsigned int i; float f; } c; c.i = ((unsigned int)u) << 16; return c.f;
}
__device__ __forceinline__ u16 f2bf(float f) {
    union { float f; unsigned int i; } c; c.f = f;
    unsigned int r = c.i + 0x7FFFu + ((c.i >> 16) & 1u);  // RNE
    return (u16)(r >> 16);
}

// ---------------------------------------------------------------------------
// Transpose f32 weight W[K][N] -> split bf16 Wt_hi/Wt_lo [N][K]
// (hi = bf16(w), lo = bf16(w - hi); w ~= hi + lo to ~2^-17 rel).
// ---------------------------------------------------------------------------
__global__ __launch_bounds__(256) void transpose_split(
    const float* __restrict__ W, u16* __restrict__ Th, u16* __restrict__ Tl,
    int K, int N)
{
    __shared__ float tile[32][33];
    const int bk = blockIdx.y * 32, bn = blockIdx.x * 32;
    const int tx = threadIdx.x & 31, ty = threadIdx.x >> 5;  // 32 x 8
    #pragma unroll
    for (int r = ty; r < 32; r += 8)
        tile[r][tx] = W[(size_t)(bk + r) * N + bn + tx];
    __syncthreads();
    #pragma unroll
    for (int r = ty; r < 32; r += 8) {
        float v = tile[tx][r];
        u16 h = f2bf(v);
        Th[(size_t)(bn + r) * K + bk + tx] = h;
        Tl[(size_t)(bn + r) * K + bk + tx] = f2bf(v - bf2f(h));
    }
}

// ---------------------------------------------------------------------------
// C[M][N] = A[M][K] @ B^T + bias, fp32-quality via 3-pass split bf16 MFMA:
//   acc += Ah*Bh + Ah*Bl + Al*Bh   (Al*Bl term ~2^-18 rel, dropped)
// A is f32 row-major (split during staging); B pre-transposed+split bf16
// [N][K]. 128x128 tile, BK=32, 4 waves in 2x2, each wave 4x4 of
// mfma_f32_16x16x32_bf16. C/D layout: col = lane&15, row = (lane>>4)*4+reg.
// A/B frag: row/col = lane&15, k = (lane>>4)*8 + j -> b128 LDS loads.
// ---------------------------------------------------------------------------
__global__ __launch_bounds__(256) void gemm_split_bias(
    const float* __restrict__ A,
    const u16* __restrict__ BtH, const u16* __restrict__ BtL,
    const float* __restrict__ bias, float* __restrict__ C,
    int M, int N, int K)
{
    __shared__ u16 Ah[128][40];   // [m][k], +8 pad (16B-align rows, break stride)
    __shared__ u16 Al[128][40];
    __shared__ u16 Bh[128][40];   // [n][k]
    __shared__ u16 Bl[128][40];
    const int t = threadIdx.x;
    const int bm = blockIdx.y * 128;
    const int bn = blockIdx.x * 128;
    const int wave = t >> 6, lane = t & 63;
    const int wm = (wave >> 1) * 64, wn = (wave & 1) * 64;
    const int m16 = lane & 15, q = lane >> 4;

    f32x4 acc[4][4];
    const f32x4 zero = {0.0f, 0.0f, 0.0f, 0.0f};
    #pragma unroll
    for (int i = 0; i < 4; ++i)
        #pragma unroll
        for (int j = 0; j < 4; ++j) acc[i][j] = zero;

    for (int k0 = 0; k0 < K; k0 += 32) {
        // stage A tile (f32 -> split bf16): 128 rows x 32 k = 1024 f4 chunks
        #pragma unroll
        for (int c0 = 0; c0 < 1024; c0 += 256) {
            const int c = c0 + t;
            const int row = c >> 3, cg = (c & 7) * 4;
            f4 v = *(const f4*)&A[(size_t)(bm + row) * K + k0 + cg];
            u16x4 h, l;
            #pragma unroll
            for (int e = 0; e < 4; ++e) {
                h[e] = f2bf(v[e]);
                l[e] = f2bf(v[e] - bf2f(h[e]));
            }
            *(u16x4*)&Ah[row][cg] = h;
            *(u16x4*)&Al[row][cg] = l;
        }
        // stage B tile from pre-split Bt: 512 chunks of 8 bf16, x2 buffers
        #pragma unroll
        for (int c0 = 0; c0 < 512; c0 += 256) {
            const int c = c0 + t;
            const int row = c >> 2, cg = (c & 3) * 8;
            *(u16x8*)&Bh[row][cg] =
                *(const u16x8*)&BtH[(size_t)(bn + row) * K + k0 + cg];
            *(u16x8*)&Bl[row][cg] =
                *(const u16x8*)&BtL[(size_t)(bn + row) * K + k0 + cg];
        }
        __syncthreads();
        bf16x8 ah[4], al[4], bh[4], bl[4];
        #pragma unroll
        for (int i = 0; i < 4; ++i) {
            ah[i] = *(const bf16x8*)&Ah[wm + i * 16 + m16][q * 8];
            al[i] = *(const bf16x8*)&Al[wm + i * 16 + m16][q * 8];
        }
        #pragma unroll
        for (int j = 0; j < 4; ++j) {
            bh[j] = *(const bf16x8*)&Bh[wn + j * 16 + m16][q * 8];
            bl[j] = *(const bf16x8*)&Bl[wn + j * 16 + m16][q * 8];
        }
        #pragma unroll
        for (int i = 0; i < 4; ++i)
            #pragma unroll
            for (int j = 0; j < 4; ++j) {
                acc[i][j] = __builtin_amdgcn_mfma_f32_16x16x32_bf16(
                    ah[i], bh[j], acc[i][j], 0, 0, 0);
                acc[i][j] = __builtin_amdgcn_mfma_f32_16x16x32_bf16(
                    ah[i], bl[j], acc[i][j], 0, 0, 0);
                acc[i][j] = __builtin_amdgcn_mfma_f32_16x16x32_bf16(
                    al[i], bh[j], acc[i][j], 0, 0, 0);
            }
        __syncthreads();
    }

    #pragma unroll
    for (int j = 0; j < 4; ++j) {
        const int col = bn + wn + j * 16 + m16;
        const float bv = bias[col];
        #pragma unroll
        for (int i = 0; i < 4; ++i) {
            const int row = bm + wm + i * 16 + q * 4;
            #pragma unroll
            for (int r = 0; r < 4; ++r)
                C[(size_t)(row + r) * N + col] = acc[i][j][r] + bv;
        }
    }
}

// ---------------------------------------------------------------------------
// In-place RMSNorm over each 64-elem head group of q and k (fp32 qkv buffer).
// One wave per (row, q|k, head).
// ---------------------------------------------------------------------------
__global__ __launch_bounds__(256) void rmsnorm_qk(
    float* __restrict__ qkv, const float* __restrict__ qw,
    const float* __restrict__ kw)
{
    const int g = blockIdx.x * 4 + (threadIdx.x >> 6);
    const int lane = threadIdx.x & 63;
    const int row = g >> 5, rem = g & 31;
    const int qk = rem >> 4, head = rem & 15;
    const size_t idx = (size_t)row * 3072 + qk * 1024 + head * 64 + lane;
    float v = qkv[idx];
    float ss = v * v;
    #pragma unroll
    for (int off = 32; off > 0; off >>= 1) ss += __shfl_xor(ss, off, 64);
    const float nrm = rsqrtf(ss * 0.015625f + 1e-6f);
    const float w = (qk ? kw : qw)[lane];
    qkv[idx] = v * nrm * w;
}

// ---------------------------------------------------------------------------
// Flash attention (online softmax), f32 vector-ALU. Block = (b,h) x 64-row
// Q tile. qkv f32 [4096][3072]: q at +0, k at +1024, v at +2048, head*64.
// S and PV register-blocked 4x4 per thread (16x16 thread grid).
// Pt aliases Kt (barrier between Kt reads and Pt writes) -> ~52 KB LDS.
// ---------------------------------------------------------------------------
__global__ __launch_bounds__(256) void flash_attn(
    const float* __restrict__ qkv, float* __restrict__ attn_out)
{
    __shared__ float Qt[64][68];   // [d][q] transposed
    __shared__ float Kt[64][68];   // [d][k] transposed; reused as Pt[k][q]
    __shared__ float Vs[64][68];   // [k][d]
    __shared__ float mstate[64], lstate[64], abuf[64];
    float (*Pt)[68] = Kt;

    const int t = threadIdx.x;
    const int qt = blockIdx.x;          // 0..31 q tile
    const int bh = blockIdx.y;          // 0..31
    const int b = bh >> 4, h = bh & 15;
    const int n0 = qt * 64;
    const size_t rowbase = (size_t)b * 2048;
    const int hoff = h * 64;

    // stage Q (transposed): 16 elems per thread
    {
        const int r = t >> 2, dgrp = (t & 3) * 16;
        const float* src = &qkv[(rowbase + n0 + r) * 3072 + hoff + dgrp];
        #pragma unroll
        for (int e = 0; e < 4; ++e) {
            f4 v = *(const f4*)&src[e * 4];
            Qt[dgrp + e * 4 + 0][r] = v[0];
            Qt[dgrp + e * 4 + 1][r] = v[1];
            Qt[dgrp + e * 4 + 2][r] = v[2];
            Qt[dgrp + e * 4 + 3][r] = v[3];
        }
    }
    if (t < 64) { mstate[t] = -1e30f; lstate[t] = 0.0f; }

    const int qg = t >> 4, kg = t & 15;
    const int q0 = qg * 4, k0 = kg * 4;  // k0 doubles as d0 in PV phase
    float O[4][4] = {};

    for (int kt = 0; kt < 32; ++kt) {
        __syncthreads();  // prev iter's Pt/Vs reads done; Q stage done
        // stage K (transposed) and V
        {
            const int r = t >> 2, dgrp = (t & 3) * 16;
            const float* ksrc =
                &qkv[(rowbase + kt * 64 + r) * 3072 + 1024 + hoff + dgrp];
            const float* vsrc = ksrc + 1024;
            #pragma unroll
            for (int e = 0; e < 4; ++e) {
                f4 kv = *(const f4*)&ksrc[e * 4];
                Kt[dgrp + e * 4 + 0][r] = kv[0];
                Kt[dgrp + e * 4 + 1][r] = kv[1];
                Kt[dgrp + e * 4 + 2][r] = kv[2];
                Kt[dgrp + e * 4 + 3][r] = kv[3];
                *(f4*)&Vs[r][dgrp + e * 4] = *(const f4*)&vsrc[e * 4];
            }
        }
        __syncthreads();
        // S = Q K^T (4x4 micro-tile per thread)
        float s[4][4] = {};
        #pragma unroll 8
        for (int d = 0; d < 64; ++d) {
            f4 qv = *(const f4*)&Qt[d][q0];
            f4 kv = *(const f4*)&Kt[d][k0];
            #pragma unroll
            for (int i = 0; i < 4; ++i)
                #pragma unroll
                for (int j = 0; j < 4; ++j) s[i][j] += qv[i] * kv[j];
        }
        __syncthreads();  // all Kt reads complete before Pt overwrite
        #pragma unroll
        for (int i = 0; i < 4; ++i)
            #pragma unroll
            for (int j = 0; j < 4; ++j)
                Pt[k0 + j][q0 + i] = s[i][j] * 0.125f;  // 1/sqrt(64)
        __syncthreads();
        // online softmax (wave 0, lane = q row)
        if (t < 64) {
            const float m_old = mstate[t];
            float mx = m_old;
            for (int k = 0; k < 64; ++k) mx = fmaxf(mx, Pt[k][t]);
            const float alpha = exp2f((m_old - mx) * 1.44269504f);
            float sum = 0.0f;
            for (int k = 0; k < 64; ++k) {
                float p = exp2f((Pt[k][t] - mx) * 1.44269504f);
                Pt[k][t] = p;
                sum += p;
            }
            lstate[t] = lstate[t] * alpha + sum;
            mstate[t] = mx;
            abuf[t] = alpha;
        }
        __syncthreads();
        // O = O*alpha + P V
        float al[4];
        #pragma unroll
        for (int i = 0; i < 4; ++i) al[i] = abuf[q0 + i];
        #pragma unroll
        for (int i = 0; i < 4; ++i)
            #pragma unroll
            for (int j = 0; j < 4; ++j) O[i][j] *= al[i];
        #pragma unroll 8
        for (int k = 0; k < 64; ++k) {
            f4 p = *(const f4*)&Pt[k][q0];
            f4 v = *(const f4*)&Vs[k][k0];
            #pragma unroll
            for (int i = 0; i < 4; ++i)
                #pragma unroll
                for (int j = 0; j < 4; ++j) O[i][j] += p[i] * v[j];
        }
    }
    __syncthreads();
    // epilogue: divide by l, store f32 to attn_out[B*N][C] at head offset
    #pragma unroll
    for (int i = 0; i < 4; ++i) {
        const float inv = 1.0f / lstate[q0 + i];
        f4 pk;
        #pragma unroll
        for (int j = 0; j < 4; ++j) pk[j] = O[i][j] * inv;
        *(f4*)&attn_out[(rowbase + n0 + q0 + i) * 1024 + hoff + k0] = pk;
    }
}

// ---------------------------------------------------------------------------
extern "C" void kernel_launch(void* const* d_in, const int* in_sizes, int n_in,
                              void* d_out, int out_size, void* d_ws, size_t ws_size,
                              hipStream_t stream)
{
    const float* x      = (const float*)d_in[0];  // [2,2048,1024] f32
    const float* qkv_w  = (const float*)d_in[1];  // [1024,3072]
    const float* qkv_b  = (const float*)d_in[2];  // [3072]
    const float* q_nw   = (const float*)d_in[3];  // [64]
    const float* k_nw   = (const float*)d_in[4];  // [64]
    const float* proj_w = (const float*)d_in[5];  // [1024,1024]
    const float* proj_b = (const float*)d_in[6];  // [1024]
    float* out = (float*)d_out;                   // [2,2048,1024] f32

    char* ws = (char*)d_ws;
    float* qkv   = (float*)ws;                    // 4096*3072 f32 = 48 MB
    float* attn  = (float*)(ws + 50331648);       // 4096*1024 f32 = 16 MB
    u16* qwT_hi  = (u16*)(ws + 67108864);         // 3072*1024 bf16 = 6 MB
    u16* qwT_lo  = (u16*)(ws + 73400320);         // 6 MB
    u16* pwT_hi  = (u16*)(ws + 79691776);         // 1024*1024 bf16 = 2 MB
    u16* pwT_lo  = (u16*)(ws + 81788928);         // 2 MB
    (void)in_sizes; (void)n_in; (void)out_size;
    // Diagnostic guard: if ws too small, emit nothing -> absmax == max|ref|.
    if (ws_size < 83886080u) return;

    transpose_split<<<dim3(3072 / 32, 1024 / 32), 256, 0, stream>>>(
        qkv_w, qwT_hi, qwT_lo, 1024, 3072);
    transpose_split<<<dim3(1024 / 32, 1024 / 32), 256, 0, stream>>>(
        proj_w, pwT_hi, pwT_lo, 1024, 1024);
    // qkv = x @ qkv_w + qkv_b  (fp32-quality, f32 out)
    gemm_split_bias<<<dim3(3072 / 128, 4096 / 128), 256, 0, stream>>>(
        x, qwT_hi, qwT_lo, qkv_b, qkv, 4096, 3072, 1024);
    // per-head RMSNorm of q and k, in place
    rmsnorm_qk<<<dim3(32768), 256, 0, stream>>>(qkv, q_nw, k_nw);
    // flash attention -> attn f32 [4096][1024]
    flash_attn<<<dim3(32, 32), 256, 0, stream>>>(qkv, attn);
    // out = attn @ proj_w + proj_b (f32 out)
    gemm_split_bias<<<dim3(1024 / 128, 4096 / 128), 256, 0, stream>>>(
        attn, pwT_hi, pwT_lo, proj_b, out, 4096, 1024, 1024);
}

// Round 3
// 350.995 us; speedup vs baseline: 2.5018x; 2.5018x over previous
//
#include <hip/hip_runtime.h>

typedef unsigned short u16;
typedef __bf16 bf16x8 __attribute__((ext_vector_type(8)));
typedef float f32x4 __attribute__((ext_vector_type(4)));
typedef unsigned short u16x8 __attribute__((ext_vector_type(8)));
typedef unsigned short u16x4 __attribute__((ext_vector_type(4)));
typedef float f4 __attribute__((ext_vector_type(4)));

__device__ __forceinline__ float bf2f(u16 u) {
    union { unsigned int i; float f; } c; c.i = ((unsigned int)u) << 16; return c.f;
}
__device__ __forceinline__ u16 f2bf(float f) {
    union { float f; unsigned int i; } c; c.f = f;
    unsigned int r = c.i + 0x7FFFu + ((c.i >> 16) & 1u);  // RNE
    return (u16)(r >> 16);
}
__device__ __forceinline__ __bf16 f2bf16(float f) {
    union { u16 u; __bf16 b; } c; c.u = f2bf(f); return c.b;
}

// ---------------------------------------------------------------------------
// Transpose f32 weight W[K][N] -> split bf16 Wt_hi/Wt_lo [N][K]
// ---------------------------------------------------------------------------
__global__ __launch_bounds__(256) void transpose_split(
    const float* __restrict__ W, u16* __restrict__ Th, u16* __restrict__ Tl,
    int K, int N)
{
    __shared__ float tile[32][33];
    const int bk = blockIdx.y * 32, bn = blockIdx.x * 32;
    const int tx = threadIdx.x & 31, ty = threadIdx.x >> 5;  // 32 x 8
    #pragma unroll
    for (int r = ty; r < 32; r += 8)
        tile[r][tx] = W[(size_t)(bk + r) * N + bn + tx];
    __syncthreads();
    #pragma unroll
    for (int r = ty; r < 32; r += 8) {
        float v = tile[tx][r];
        u16 h = f2bf(v);
        Th[(size_t)(bn + r) * K + bk + tx] = h;
        Tl[(size_t)(bn + r) * K + bk + tx] = f2bf(v - bf2f(h));
    }
}

// ---------------------------------------------------------------------------
// C[M][N] = A[M][K] @ B^T + bias, fp32-quality via 3-pass split bf16 MFMA.
// (unchanged from R2 — known-good)
// ---------------------------------------------------------------------------
__global__ __launch_bounds__(256) void gemm_split_bias(
    const float* __restrict__ A,
    const u16* __restrict__ BtH, const u16* __restrict__ BtL,
    const float* __restrict__ bias, float* __restrict__ C,
    int M, int N, int K)
{
    __shared__ u16 Ah[128][40];
    __shared__ u16 Al[128][40];
    __shared__ u16 Bh[128][40];
    __shared__ u16 Bl[128][40];
    const int t = threadIdx.x;
    const int bm = blockIdx.y * 128;
    const int bn = blockIdx.x * 128;
    const int wave = t >> 6, lane = t & 63;
    const int wm = (wave >> 1) * 64, wn = (wave & 1) * 64;
    const int m16 = lane & 15, q = lane >> 4;

    f32x4 acc[4][4];
    const f32x4 zero = {0.0f, 0.0f, 0.0f, 0.0f};
    #pragma unroll
    for (int i = 0; i < 4; ++i)
        #pragma unroll
        for (int j = 0; j < 4; ++j) acc[i][j] = zero;

    for (int k0 = 0; k0 < K; k0 += 32) {
        #pragma unroll
        for (int c0 = 0; c0 < 1024; c0 += 256) {
            const int c = c0 + t;
            const int row = c >> 3, cg = (c & 7) * 4;
            f4 v = *(const f4*)&A[(size_t)(bm + row) * K + k0 + cg];
            u16x4 h, l;
            #pragma unroll
            for (int e = 0; e < 4; ++e) {
                h[e] = f2bf(v[e]);
                l[e] = f2bf(v[e] - bf2f(h[e]));
            }
            *(u16x4*)&Ah[row][cg] = h;
            *(u16x4*)&Al[row][cg] = l;
        }
        #pragma unroll
        for (int c0 = 0; c0 < 512; c0 += 256) {
            const int c = c0 + t;
            const int row = c >> 2, cg = (c & 3) * 8;
            *(u16x8*)&Bh[row][cg] =
                *(const u16x8*)&BtH[(size_t)(bn + row) * K + k0 + cg];
            *(u16x8*)&Bl[row][cg] =
                *(const u16x8*)&BtL[(size_t)(bn + row) * K + k0 + cg];
        }
        __syncthreads();
        bf16x8 ah[4], al[4], bh[4], bl[4];
        #pragma unroll
        for (int i = 0; i < 4; ++i) {
            ah[i] = *(const bf16x8*)&Ah[wm + i * 16 + m16][q * 8];
            al[i] = *(const bf16x8*)&Al[wm + i * 16 + m16][q * 8];
        }
        #pragma unroll
        for (int j = 0; j < 4; ++j) {
            bh[j] = *(const bf16x8*)&Bh[wn + j * 16 + m16][q * 8];
            bl[j] = *(const bf16x8*)&Bl[wn + j * 16 + m16][q * 8];
        }
        #pragma unroll
        for (int i = 0; i < 4; ++i)
            #pragma unroll
            for (int j = 0; j < 4; ++j) {
                acc[i][j] = __builtin_amdgcn_mfma_f32_16x16x32_bf16(
                    ah[i], bh[j], acc[i][j], 0, 0, 0);
                acc[i][j] = __builtin_amdgcn_mfma_f32_16x16x32_bf16(
                    ah[i], bl[j], acc[i][j], 0, 0, 0);
                acc[i][j] = __builtin_amdgcn_mfma_f32_16x16x32_bf16(
                    al[i], bh[j], acc[i][j], 0, 0, 0);
            }
        __syncthreads();
    }

    #pragma unroll
    for (int j = 0; j < 4; ++j) {
        const int col = bn + wn + j * 16 + m16;
        const float bv = bias[col];
        #pragma unroll
        for (int i = 0; i < 4; ++i) {
            const int row = bm + wm + i * 16 + q * 4;
            #pragma unroll
            for (int r = 0; r < 4; ++r)
                C[(size_t)(row + r) * N + col] = acc[i][j][r] + bv;
        }
    }
}

// ---------------------------------------------------------------------------
// RMSNorm q,k head groups (from f32 qkv) -> bf16 Qb/Kb [(b*16+h)*2048+n][64].
// One wave per (row, q|k, head).
// ---------------------------------------------------------------------------
__global__ __launch_bounds__(256) void rms_convert(
    const float* __restrict__ qkv, const float* __restrict__ qw,
    const float* __restrict__ kw, u16* __restrict__ Qb, u16* __restrict__ Kb)
{
    const int g = blockIdx.x * 4 + (threadIdx.x >> 6);
    const int lane = threadIdx.x & 63;
    const int row = g >> 5, rem = g & 31;
    const int qk = rem >> 4, head = rem & 15;
    const float v = qkv[(size_t)row * 3072 + qk * 1024 + head * 64 + lane];
    float ss = v * v;
    #pragma unroll
    for (int off = 32; off > 0; off >>= 1) ss += __shfl_xor(ss, off, 64);
    const float nrm = rsqrtf(ss * 0.015625f + 1e-6f);
    const float w = (qk ? kw : qw)[lane];
    u16* dst = qk ? Kb : Qb;
    const size_t didx =
        ((size_t)((row >> 11) * 16 + head) * 2048 + (row & 2047)) * 64 + lane;
    dst[didx] = f2bf(v * nrm * w);
}

// ---------------------------------------------------------------------------
// V part of qkv (f32 [n][d] per (b,h)) -> Vt bf16 [(b*16+h)][d][2048].
// 32x32 tiled transpose. grid (ntile=64, dtile=2, bh=32).
// ---------------------------------------------------------------------------
__global__ __launch_bounds__(256) void v_transpose(
    const float* __restrict__ qkv, u16* __restrict__ Vt)
{
    __shared__ float tile[32][33];
    const int nt = blockIdx.x, dt = blockIdx.y, bh = blockIdx.z;
    const int b = bh >> 4, h = bh & 15;
    const int tx = threadIdx.x & 31, ty = threadIdx.x >> 5;
    #pragma unroll
    for (int r = ty; r < 32; r += 8) {
        const size_t row = (size_t)b * 2048 + nt * 32 + r;
        tile[r][tx] = qkv[row * 3072 + 2048 + h * 64 + dt * 32 + tx];
    }
    __syncthreads();
    #pragma unroll
    for (int r = ty; r < 32; r += 8)
        Vt[((size_t)bh * 64 + dt * 32 + r) * 2048 + nt * 32 + tx] =
            f2bf(tile[tx][r]);
}

// ---------------------------------------------------------------------------
// MFMA flash attention. Block = 256 thr (4 waves) = (bh, 64-row Q tile).
// Wave w owns q rows [w*16, w*16+16). K-tile = 64 keys, d = 64.
// S = Q K^T and O = P V via mfma_f32_16x16x32_bf16.
// Static-max softmax (|s| <= 8 by RMSNorm Cauchy-Schwarz -> no overflow):
//   p = exp2(s*0.125*log2e), l accumulated as per-lane partials, reduced once
//   at the end. P round-trips LDS (D-layout writes -> A-layout b128 reads);
//   in-wave DS ops are in-order, no barrier needed for the P round-trip.
// ---------------------------------------------------------------------------
__global__ __launch_bounds__(256) void flash_attn_mfma(
    const u16* __restrict__ Qb, const u16* __restrict__ Kb,
    const u16* __restrict__ Vt, float* __restrict__ attn_out)
{
    __shared__ u16 Qlds[64][72];   // [q][d]   stride 144B (16B mult)
    __shared__ u16 Klds[64][72];   // [key][d]
    __shared__ u16 Vlds[64][72];   // [d][key]
    __shared__ u16 Plds[64][80];   // [q][key] stride 160B (16B mult)

    const int t = threadIdx.x;
    const int qt = blockIdx.x;     // 0..31
    const int bh = blockIdx.y;     // 0..31
    const int n0 = qt * 64;
    const size_t qbase = ((size_t)bh * 2048 + n0) * 64;
    const size_t kbase = (size_t)bh * 2048 * 64;
    const size_t vbase = (size_t)bh * 64 * 2048;
    const int wave = t >> 6, lane = t & 63;
    const int l15 = lane & 15, quad = lane >> 4;
    const int sr = t >> 2, seg = (t & 3) * 16;   // staging: row 0..63, 16-elem seg

    // stage Q once (bf16, contiguous)
    *(u16x8*)&Qlds[sr][seg]     = *(const u16x8*)&Qb[qbase + sr * 64 + seg];
    *(u16x8*)&Qlds[sr][seg + 8] = *(const u16x8*)&Qb[qbase + sr * 64 + seg + 8];
    __syncthreads();
    bf16x8 qf0 = *(const bf16x8*)&Qlds[wave * 16 + l15][quad * 8];
    bf16x8 qf1 = *(const bf16x8*)&Qlds[wave * 16 + l15][quad * 8 + 32];

    f32x4 o[4];
    const f32x4 zero = {0.0f, 0.0f, 0.0f, 0.0f};
    #pragma unroll
    for (int dt = 0; dt < 4; ++dt) o[dt] = zero;
    float lsum[4] = {0.0f, 0.0f, 0.0f, 0.0f};
    const float SC = 0.125f * 1.44269504f;   // 1/sqrt(64) * log2(e)

    for (int kt = 0; kt < 32; ++kt) {
        __syncthreads();   // prior iter's Klds/Vlds frag reads complete
        {   // stage K and V tiles (bf16, contiguous)
            const size_t ko = kbase + (size_t)(kt * 64 + sr) * 64 + seg;
            *(u16x8*)&Klds[sr][seg]     = *(const u16x8*)&Kb[ko];
            *(u16x8*)&Klds[sr][seg + 8] = *(const u16x8*)&Kb[ko + 8];
            const size_t vo = vbase + (size_t)sr * 2048 + kt * 64 + seg;
            *(u16x8*)&Vlds[sr][seg]     = *(const u16x8*)&Vt[vo];
            *(u16x8*)&Vlds[sr][seg + 8] = *(const u16x8*)&Vt[vo + 8];
        }
        __syncthreads();

        // S = Q K^T : 4 key-tiles x 2 k-steps
        f32x4 s[4];
        #pragma unroll
        for (int nt = 0; nt < 4; ++nt) {
            s[nt] = zero;
            bf16x8 kf0 = *(const bf16x8*)&Klds[nt * 16 + l15][quad * 8];
            bf16x8 kf1 = *(const bf16x8*)&Klds[nt * 16 + l15][quad * 8 + 32];
            s[nt] = __builtin_amdgcn_mfma_f32_16x16x32_bf16(qf0, kf0, s[nt], 0, 0, 0);
            s[nt] = __builtin_amdgcn_mfma_f32_16x16x32_bf16(qf1, kf1, s[nt], 0, 0, 0);
        }

        // p = exp2(s/8 * log2e); accumulate per-lane partial row sums
        float p[4][4];
        #pragma unroll
        for (int nt = 0; nt < 4; ++nt)
            #pragma unroll
            for (int r = 0; r < 4; ++r)
                p[nt][r] = exp2f(s[nt][r] * SC);
        #pragma unroll
        for (int r = 0; r < 4; ++r)
            lsum[r] += (p[0][r] + p[1][r]) + (p[2][r] + p[3][r]);

        // write P (bf16) in D-layout to this wave's Plds rows
        #pragma unroll
        for (int nt = 0; nt < 4; ++nt)
            #pragma unroll
            for (int r = 0; r < 4; ++r)
                Plds[wave * 16 + quad * 4 + r][nt * 16 + l15] = f2bf(p[nt][r]);

        // read P back in A-layout (in-wave DS order guarantees visibility)
        bf16x8 pf0 = *(const bf16x8*)&Plds[wave * 16 + l15][quad * 8];
        bf16x8 pf1 = *(const bf16x8*)&Plds[wave * 16 + l15][quad * 8 + 32];

        // O += P V : 4 d-tiles x 2 k-steps
        #pragma unroll
        for (int dt = 0; dt < 4; ++dt) {
            bf16x8 vf0 = *(const bf16x8*)&Vlds[dt * 16 + l15][quad * 8];
            bf16x8 vf1 = *(const bf16x8*)&Vlds[dt * 16 + l15][quad * 8 + 32];
            o[dt] = __builtin_amdgcn_mfma_f32_16x16x32_bf16(pf0, vf0, o[dt], 0, 0, 0);
            o[dt] = __builtin_amdgcn_mfma_f32_16x16x32_bf16(pf1, vf1, o[dt], 0, 0, 0);
        }
    }

    // final l reduction across the 16 key-slices (lanes differing in l15)
    #pragma unroll
    for (int r = 0; r < 4; ++r) {
        #pragma unroll
        for (int m = 1; m < 16; m <<= 1) lsum[r] += __shfl_xor(lsum[r], m, 64);
    }
    // epilogue: O/l -> attn_out f32 [B*N][1024]
    const size_t obase =
        ((size_t)(bh >> 4) * 2048 + n0) * 1024 + (bh & 15) * 64;
    #pragma unroll
    for (int r = 0; r < 4; ++r) {
        const float inv = 1.0f / lsum[r];
        const size_t rbase = obase + (size_t)(wave * 16 + quad * 4 + r) * 1024;
        #pragma unroll
        for (int dt = 0; dt < 4; ++dt)
            attn_out[rbase + dt * 16 + l15] = o[dt][r] * inv;
    }
}

// ---------------------------------------------------------------------------
extern "C" void kernel_launch(void* const* d_in, const int* in_sizes, int n_in,
                              void* d_out, int out_size, void* d_ws, size_t ws_size,
                              hipStream_t stream)
{
    const float* x      = (const float*)d_in[0];  // [2,2048,1024] f32
    const float* qkv_w  = (const float*)d_in[1];  // [1024,3072]
    const float* qkv_b  = (const float*)d_in[2];  // [3072]
    const float* q_nw   = (const float*)d_in[3];  // [64]
    const float* k_nw   = (const float*)d_in[4];  // [64]
    const float* proj_w = (const float*)d_in[5];  // [1024,1024]
    const float* proj_b = (const float*)d_in[6];  // [1024]
    float* out = (float*)d_out;                   // [2,2048,1024] f32

    // ws layout (80 MB, with lifetime-based aliasing):
    //  [0,48M)   qkv f32        (dead after rms_convert + v_transpose)
    //  [0,16M)   attn f32       (aliases dead qkv; written by flash)
    //  [48,54M)  qkv_wT_hi      (dead after gemm1)
    //  [54,60M)  qkv_wT_lo      (dead after gemm1)
    //  [48,56M)  Vt bf16        (aliases dead qkv_wT; written by v_transpose)
    //  [60,62M)  proj_wT_hi     (live until gemm2)
    //  [62,64M)  proj_wT_lo
    //  [64,72M)  Qb bf16
    //  [72,80M)  Kb bf16
    char* ws = (char*)d_ws;
    float* qkv   = (float*)ws;
    float* attn  = (float*)ws;
    u16* qwT_hi  = (u16*)(ws + 50331648);
    u16* qwT_lo  = (u16*)(ws + 56623104);
    u16* VtB     = (u16*)(ws + 50331648);
    u16* pwT_hi  = (u16*)(ws + 62914560);
    u16* pwT_lo  = (u16*)(ws + 65011712);
    u16* QbB     = (u16*)(ws + 67108864);
    u16* KbB     = (u16*)(ws + 75497472);
    (void)in_sizes; (void)n_in; (void)out_size;
    // Diagnostic guard: if ws too small, emit nothing -> absmax == max|ref|.
    if (ws_size < 83886080u) return;

    transpose_split<<<dim3(3072 / 32, 1024 / 32), 256, 0, stream>>>(
        qkv_w, qwT_hi, qwT_lo, 1024, 3072);
    transpose_split<<<dim3(1024 / 32, 1024 / 32), 256, 0, stream>>>(
        proj_w, pwT_hi, pwT_lo, 1024, 1024);
    // qkv = x @ qkv_w + qkv_b (fp32-quality, f32 out)
    gemm_split_bias<<<dim3(3072 / 128, 4096 / 128), 256, 0, stream>>>(
        x, qwT_hi, qwT_lo, qkv_b, qkv, 4096, 3072, 1024);
    // per-head RMSNorm of q,k -> bf16 Qb/Kb [bh][n][64]
    rms_convert<<<dim3(32768), 256, 0, stream>>>(qkv, q_nw, k_nw, QbB, KbB);
    // v -> bf16 Vt [bh][d][n]   (overwrites dead qkv_wT region)
    v_transpose<<<dim3(64, 2, 32), 256, 0, stream>>>(qkv, VtB);
    // flash attention -> attn f32 [4096][1024]  (overwrites dead qkv region)
    flash_attn_mfma<<<dim3(32, 32), 256, 0, stream>>>(QbB, KbB, VtB, attn);
    // out = attn @ proj_w + proj_b (f32 out)
    gemm_split_bias<<<dim3(1024 / 128, 4096 / 128), 256, 0, stream>>>(
        attn, pwT_hi, pwT_lo, proj_b, out, 4096, 1024, 1024);
}

// Round 4
// 311.392 us; speedup vs baseline: 2.8200x; 1.1272x over previous
//
#include <hip/hip_runtime.h>

typedef unsigned short u16;
typedef unsigned int u32;
typedef __bf16 bf16x8 __attribute__((ext_vector_type(8)));
typedef float f32x4 __attribute__((ext_vector_type(4)));
typedef unsigned short u16x8 __attribute__((ext_vector_type(8)));
typedef unsigned short u16x4 __attribute__((ext_vector_type(4)));
typedef float f4 __attribute__((ext_vector_type(4)));

__device__ __forceinline__ float bf2f(u16 u) {
    union { unsigned int i; float f; } c; c.i = ((unsigned int)u) << 16; return c.f;
}
__device__ __forceinline__ u16 f2bf(float f) {
    union { float f; unsigned int i; } c; c.f = f;
    unsigned int r = c.i + 0x7FFFu + ((c.i >> 16) & 1u);  // RNE
    return (u16)(r >> 16);
}
// async global->LDS, 16B/lane; LDS dest = wave-uniform base + lane*16
__device__ __forceinline__ void async16(const void* g, void* l) {
    __builtin_amdgcn_global_load_lds(
        (const __attribute__((address_space(1))) u32*)g,
        (__attribute__((address_space(3))) u32*)l, 16, 0, 0);
}

// ---------------------------------------------------------------------------
// x f32 -> split bf16 (hi, lo): elementwise, 4 elems/thread.
// ---------------------------------------------------------------------------
__global__ __launch_bounds__(256) void split_x(
    const float* __restrict__ X, u16* __restrict__ H, u16* __restrict__ L)
{
    const size_t i = ((size_t)blockIdx.x * 256 + threadIdx.x) * 4;
    f4 v = *(const f4*)&X[i];
    u16x4 h, l;
    #pragma unroll
    for (int e = 0; e < 4; ++e) {
        h[e] = f2bf(v[e]);
        l[e] = f2bf(v[e] - bf2f(h[e]));
    }
    *(u16x4*)&H[i] = h;
    *(u16x4*)&L[i] = l;
}

// ---------------------------------------------------------------------------
// Transpose f32 weight W[K][N] -> split bf16 Wt_hi/Wt_lo [N][K]
// ---------------------------------------------------------------------------
__global__ __launch_bounds__(256) void transpose_split(
    const float* __restrict__ W, u16* __restrict__ Th, u16* __restrict__ Tl,
    int K, int N)
{
    __shared__ float tile[32][33];
    const int bk = blockIdx.y * 32, bn = blockIdx.x * 32;
    const int tx = threadIdx.x & 31, ty = threadIdx.x >> 5;  // 32 x 8
    #pragma unroll
    for (int r = ty; r < 32; r += 8)
        tile[r][tx] = W[(size_t)(bk + r) * N + bn + tx];
    __syncthreads();
    #pragma unroll
    for (int r = ty; r < 32; r += 8) {
        float v = tile[tx][r];
        u16 h = f2bf(v);
        Th[(size_t)(bn + r) * K + bk + tx] = h;
        Tl[(size_t)(bn + r) * K + bk + tx] = f2bf(v - bf2f(h));
    }
}

// ---------------------------------------------------------------------------
// Fused GEMM: C = A @ B^T + bias, fp32-quality via 3-pass split bf16 MFMA
// (Ah*Bh + Ah*Bl + Al*Bh). A pre-split bf16 [M][K] (hi,lo); B pre-split
// transposed bf16 [N][K]. 128x128 tile, BK=32, 4 waves 2x2, 4x4 MFMA each.
// Staging via global_load_lds width=16 into unpadded [128][32] LDS (m97).
// EPI==0 (QKV): epilogue fuses per-head RMSNorm -> Qb/Kb bf16 [bh][n][64]
//               and V transpose -> Vt bf16 [bh][d][n].
// EPI==1 (proj): bias + f32 store.
// C/D layout: col = lane&15, row = (lane>>4)*4 + reg (verified m89/m91).
// ---------------------------------------------------------------------------
template <int EPI>
__global__ __launch_bounds__(256) void gemm_fused(
    const u16* __restrict__ AH, const u16* __restrict__ AL,
    const u16* __restrict__ BH, const u16* __restrict__ BL,
    const float* __restrict__ bias, float* __restrict__ C,
    u16* __restrict__ Qb, u16* __restrict__ Kb, u16* __restrict__ Vt,
    const float* __restrict__ qw, const float* __restrict__ kw,
    int M, int N, int K)
{
    __shared__ __align__(16) u16 AhT[128 * 32];
    __shared__ __align__(16) u16 AlT[128 * 32];
    __shared__ __align__(16) u16 BhT[128 * 32];
    __shared__ __align__(16) u16 BlT[128 * 32];
    const int t = threadIdx.x;
    const int bm = blockIdx.y * 128, bn = blockIdx.x * 128;
    const int wave = t >> 6, lane = t & 63;
    const int wm = (wave >> 1) * 64, wn = (wave & 1) * 64;
    const int l15 = lane & 15, quad = lane >> 4;
    const int srow = lane >> 2, scol = (lane & 3) * 8;  // staging row/col

    f32x4 acc[4][4];
    const f32x4 zero = {0.0f, 0.0f, 0.0f, 0.0f};
    #pragma unroll
    for (int i = 0; i < 4; ++i)
        #pragma unroll
        for (int j = 0; j < 4; ++j) acc[i][j] = zero;

    for (int k0 = 0; k0 < K; k0 += 32) {
        #pragma unroll
        for (int rr = 0; rr < 2; ++rr) {
            const int r0 = (rr * 4 + wave) * 16;   // 16 rows per wave-call
            const size_t ga = (size_t)(bm + r0 + srow) * K + k0 + scol;
            const size_t gb = (size_t)(bn + r0 + srow) * K + k0 + scol;
            async16(&AH[ga], &AhT[r0 * 32]);
            async16(&AL[ga], &AlT[r0 * 32]);
            async16(&BH[gb], &BhT[r0 * 32]);
            async16(&BL[gb], &BlT[r0 * 32]);
        }
        __syncthreads();   // vmcnt(0) drain + barrier
        bf16x8 ah[4], al[4], bh[4], bl[4];
        #pragma unroll
        for (int i = 0; i < 4; ++i) {
            ah[i] = *(const bf16x8*)&AhT[(wm + i * 16 + l15) * 32 + quad * 8];
            al[i] = *(const bf16x8*)&AlT[(wm + i * 16 + l15) * 32 + quad * 8];
        }
        #pragma unroll
        for (int j = 0; j < 4; ++j) {
            bh[j] = *(const bf16x8*)&BhT[(wn + j * 16 + l15) * 32 + quad * 8];
            bl[j] = *(const bf16x8*)&BlT[(wn + j * 16 + l15) * 32 + quad * 8];
        }
        #pragma unroll
        for (int i = 0; i < 4; ++i)
            #pragma unroll
            for (int j = 0; j < 4; ++j) {
                acc[i][j] = __builtin_amdgcn_mfma_f32_16x16x32_bf16(
                    ah[i], bh[j], acc[i][j], 0, 0, 0);
                acc[i][j] = __builtin_amdgcn_mfma_f32_16x16x32_bf16(
                    ah[i], bl[j], acc[i][j], 0, 0, 0);
                acc[i][j] = __builtin_amdgcn_mfma_f32_16x16x32_bf16(
                    al[i], bh[j], acc[i][j], 0, 0, 0);
            }
        __syncthreads();   // frag reads done before next staging overwrite
    }

    if (EPI == 1) {
        #pragma unroll
        for (int j = 0; j < 4; ++j) {
            const int col = bn + wn + j * 16 + l15;
            const float bv = bias[col];
            #pragma unroll
            for (int i = 0; i < 4; ++i) {
                const int row = bm + wm + i * 16 + quad * 4;
                #pragma unroll
                for (int r = 0; r < 4; ++r)
                    C[(size_t)(row + r) * N + col] = acc[i][j][r] + bv;
            }
        }
    } else {
        // wave's 64-col group = one (section, head) pair: gc0 is 64-aligned.
        const int gc0 = bn + wn;
        const int sec = gc0 >> 10;              // 0=q, 1=k, 2=v
        const int h = (gc0 & 1023) >> 6;
        const int b = bm >> 11;                 // uniform: 128-row tile in one b
        const int bhd = b * 16 + h;
        float bv[4], wj[4];
        #pragma unroll
        for (int j = 0; j < 4; ++j) {
            const int d = j * 16 + l15;
            bv[j] = bias[gc0 + d];
            wj[j] = (sec == 2) ? 0.0f : (sec ? kw : qw)[d];
        }
        if (sec < 2) {
            u16* dst = sec ? Kb : Qb;
            #pragma unroll
            for (int i = 0; i < 4; ++i) {
                float val[4][4];   // [j][r]
                float ss[4] = {0.0f, 0.0f, 0.0f, 0.0f};
                #pragma unroll
                for (int j = 0; j < 4; ++j)
                    #pragma unroll
                    for (int r = 0; r < 4; ++r) {
                        val[j][r] = acc[i][j][r] + bv[j];
                        ss[r] += val[j][r] * val[j][r];
                    }
                #pragma unroll
                for (int r = 0; r < 4; ++r) {
                    #pragma unroll
                    for (int m = 1; m < 16; m <<= 1)
                        ss[r] += __shfl_xor(ss[r], m, 64);
                    const float nrm = rsqrtf(ss[r] * 0.015625f + 1e-6f);
                    const int n = (bm + wm + i * 16 + quad * 4 + r) & 2047;
                    const size_t rowb = ((size_t)bhd * 2048 + n) * 64;
                    #pragma unroll
                    for (int j = 0; j < 4; ++j)
                        dst[rowb + j * 16 + l15] = f2bf(val[j][r] * nrm * wj[j]);
                }
            }
        } else {
            #pragma unroll
            for (int i = 0; i < 4; ++i) {
                const int n0 = (bm + wm + i * 16 + quad * 4) & 2047;
                #pragma unroll
                for (int j = 0; j < 4; ++j) {
                    const int d = j * 16 + l15;
                    u16x4 pk;
                    #pragma unroll
                    for (int r = 0; r < 4; ++r)
                        pk[r] = f2bf(acc[i][j][r] + bv[j]);
                    *(u16x4*)&Vt[((size_t)bhd * 64 + d) * 2048 + n0] = pk;
                }
            }
        }
    }
}

// ---------------------------------------------------------------------------
// MFMA flash attention (unchanged core; epilogue now emits split bf16).
// Block = 4 waves = (bh, 64-row Q tile); static-max softmax (|s| <= 8).
// ---------------------------------------------------------------------------
__global__ __launch_bounds__(256) void flash_attn_mfma(
    const u16* __restrict__ Qb, const u16* __restrict__ Kb,
    const u16* __restrict__ Vt, u16* __restrict__ AttnH, u16* __restrict__ AttnL)
{
    __shared__ u16 Qlds[64][72];
    __shared__ u16 Klds[64][72];
    __shared__ u16 Vlds[64][72];
    __shared__ u16 Plds[64][80];

    const int t = threadIdx.x;
    const int qt = blockIdx.x;     // 0..31
    const int bh = blockIdx.y;     // 0..31
    const int n0 = qt * 64;
    const size_t qbase = ((size_t)bh * 2048 + n0) * 64;
    const size_t kbase = (size_t)bh * 2048 * 64;
    const size_t vbase = (size_t)bh * 64 * 2048;
    const int wave = t >> 6, lane = t & 63;
    const int l15 = lane & 15, quad = lane >> 4;
    const int sr = t >> 2, seg = (t & 3) * 16;

    *(u16x8*)&Qlds[sr][seg]     = *(const u16x8*)&Qb[qbase + sr * 64 + seg];
    *(u16x8*)&Qlds[sr][seg + 8] = *(const u16x8*)&Qb[qbase + sr * 64 + seg + 8];
    __syncthreads();
    bf16x8 qf0 = *(const bf16x8*)&Qlds[wave * 16 + l15][quad * 8];
    bf16x8 qf1 = *(const bf16x8*)&Qlds[wave * 16 + l15][quad * 8 + 32];

    f32x4 o[4];
    const f32x4 zero = {0.0f, 0.0f, 0.0f, 0.0f};
    #pragma unroll
    for (int dt = 0; dt < 4; ++dt) o[dt] = zero;
    float lsum[4] = {0.0f, 0.0f, 0.0f, 0.0f};
    const float SC = 0.125f * 1.44269504f;

    for (int kt = 0; kt < 32; ++kt) {
        __syncthreads();
        {
            const size_t ko = kbase + (size_t)(kt * 64 + sr) * 64 + seg;
            *(u16x8*)&Klds[sr][seg]     = *(const u16x8*)&Kb[ko];
            *(u16x8*)&Klds[sr][seg + 8] = *(const u16x8*)&Kb[ko + 8];
            const size_t vo = vbase + (size_t)sr * 2048 + kt * 64 + seg;
            *(u16x8*)&Vlds[sr][seg]     = *(const u16x8*)&Vt[vo];
            *(u16x8*)&Vlds[sr][seg + 8] = *(const u16x8*)&Vt[vo + 8];
        }
        __syncthreads();

        f32x4 s[4];
        #pragma unroll
        for (int nt = 0; nt < 4; ++nt) {
            s[nt] = zero;
            bf16x8 kf0 = *(const bf16x8*)&Klds[nt * 16 + l15][quad * 8];
            bf16x8 kf1 = *(const bf16x8*)&Klds[nt * 16 + l15][quad * 8 + 32];
            s[nt] = __builtin_amdgcn_mfma_f32_16x16x32_bf16(qf0, kf0, s[nt], 0, 0, 0);
            s[nt] = __builtin_amdgcn_mfma_f32_16x16x32_bf16(qf1, kf1, s[nt], 0, 0, 0);
        }

        float p[4][4];
        #pragma unroll
        for (int nt = 0; nt < 4; ++nt)
            #pragma unroll
            for (int r = 0; r < 4; ++r)
                p[nt][r] = exp2f(s[nt][r] * SC);
        #pragma unroll
        for (int r = 0; r < 4; ++r)
            lsum[r] += (p[0][r] + p[1][r]) + (p[2][r] + p[3][r]);

        #pragma unroll
        for (int nt = 0; nt < 4; ++nt)
            #pragma unroll
            for (int r = 0; r < 4; ++r)
                Plds[wave * 16 + quad * 4 + r][nt * 16 + l15] = f2bf(p[nt][r]);

        bf16x8 pf0 = *(const bf16x8*)&Plds[wave * 16 + l15][quad * 8];
        bf16x8 pf1 = *(const bf16x8*)&Plds[wave * 16 + l15][quad * 8 + 32];

        #pragma unroll
        for (int dt = 0; dt < 4; ++dt) {
            bf16x8 vf0 = *(const bf16x8*)&Vlds[dt * 16 + l15][quad * 8];
            bf16x8 vf1 = *(const bf16x8*)&Vlds[dt * 16 + l15][quad * 8 + 32];
            o[dt] = __builtin_amdgcn_mfma_f32_16x16x32_bf16(pf0, vf0, o[dt], 0, 0, 0);
            o[dt] = __builtin_amdgcn_mfma_f32_16x16x32_bf16(pf1, vf1, o[dt], 0, 0, 0);
        }
    }

    #pragma unroll
    for (int r = 0; r < 4; ++r) {
        #pragma unroll
        for (int m = 1; m < 16; m <<= 1) lsum[r] += __shfl_xor(lsum[r], m, 64);
    }
    const size_t obase =
        ((size_t)(bh >> 4) * 2048 + n0) * 1024 + (bh & 15) * 64;
    #pragma unroll
    for (int r = 0; r < 4; ++r) {
        const float inv = 1.0f / lsum[r];
        const size_t rbase = obase + (size_t)(wave * 16 + quad * 4 + r) * 1024;
        #pragma unroll
        for (int dt = 0; dt < 4; ++dt) {
            const float v = o[dt][r] * inv;
            const u16 hh = f2bf(v);
            AttnH[rbase + dt * 16 + l15] = hh;
            AttnL[rbase + dt * 16 + l15] = f2bf(v - bf2f(hh));
        }
    }
}

// ---------------------------------------------------------------------------
extern "C" void kernel_launch(void* const* d_in, const int* in_sizes, int n_in,
                              void* d_out, int out_size, void* d_ws, size_t ws_size,
                              hipStream_t stream)
{
    const float* x      = (const float*)d_in[0];  // [2,2048,1024] f32
    const float* qkv_w  = (const float*)d_in[1];  // [1024,3072]
    const float* qkv_b  = (const float*)d_in[2];  // [3072]
    const float* q_nw   = (const float*)d_in[3];  // [64]
    const float* k_nw   = (const float*)d_in[4];  // [64]
    const float* proj_w = (const float*)d_in[5];  // [1024,1024]
    const float* proj_b = (const float*)d_in[6];  // [1024]
    float* out = (float*)d_out;                   // [2,2048,1024] f32

    // ws layout (72 MB, no aliasing):
    //  [0,8M)    AttnH bf16   [8,16M)  AttnL bf16
    //  [16,22M)  qwT_hi       [22,28M) qwT_lo
    //  [28,30M)  pwT_hi       [30,32M) pwT_lo
    //  [32,40M)  Xh bf16      [40,48M) Xl bf16
    //  [48,56M)  Qb bf16      [56,64M) Kb bf16   [64,72M) Vt bf16
    char* ws = (char*)d_ws;
    u16* AttnH  = (u16*)ws;
    u16* AttnL  = (u16*)(ws + 8388608);
    u16* qwT_hi = (u16*)(ws + 16777216);
    u16* qwT_lo = (u16*)(ws + 23068672);
    u16* pwT_hi = (u16*)(ws + 29360128);
    u16* pwT_lo = (u16*)(ws + 31457280);
    u16* Xh     = (u16*)(ws + 33554432);
    u16* Xl     = (u16*)(ws + 41943040);
    u16* QbB    = (u16*)(ws + 50331648);
    u16* KbB    = (u16*)(ws + 58720256);
    u16* VtB    = (u16*)(ws + 67108864);
    (void)in_sizes; (void)n_in; (void)out_size;
    // Diagnostic guard: if ws too small, emit nothing -> absmax == max|ref|.
    if (ws_size < 83886080u) return;

    split_x<<<dim3(4096), 256, 0, stream>>>(x, Xh, Xl);
    transpose_split<<<dim3(3072 / 32, 1024 / 32), 256, 0, stream>>>(
        qkv_w, qwT_hi, qwT_lo, 1024, 3072);
    transpose_split<<<dim3(1024 / 32, 1024 / 32), 256, 0, stream>>>(
        proj_w, pwT_hi, pwT_lo, 1024, 1024);
    // QKV GEMM with fused bias + RMSNorm + head-split/transpose epilogue
    gemm_fused<0><<<dim3(3072 / 128, 4096 / 128), 256, 0, stream>>>(
        Xh, Xl, qwT_hi, qwT_lo, qkv_b, nullptr,
        QbB, KbB, VtB, q_nw, k_nw, 4096, 3072, 1024);
    // flash attention -> AttnH/AttnL split bf16
    flash_attn_mfma<<<dim3(32, 32), 256, 0, stream>>>(
        QbB, KbB, VtB, AttnH, AttnL);
    // out = attn @ proj_w + proj_b (f32)
    gemm_fused<1><<<dim3(1024 / 128, 4096 / 128), 256, 0, stream>>>(
        AttnH, AttnL, pwT_hi, pwT_lo, proj_b, out,
        nullptr, nullptr, nullptr, nullptr, nullptr, 4096, 1024, 1024);
}

// Round 6
// 249.816 us; speedup vs baseline: 3.5151x; 1.2465x over previous
//
#include <hip/hip_runtime.h>

typedef unsigned short u16;
typedef unsigned int u32;
typedef __bf16 bf16x8 __attribute__((ext_vector_type(8)));
typedef float f32x4 __attribute__((ext_vector_type(4)));
typedef unsigned short u16x8 __attribute__((ext_vector_type(8)));
typedef unsigned short u16x4 __attribute__((ext_vector_type(4)));
typedef float f4 __attribute__((ext_vector_type(4)));

__device__ __forceinline__ float bf2f(u16 u) {
    union { unsigned int i; float f; } c; c.i = ((unsigned int)u) << 16; return c.f;
}
__device__ __forceinline__ u16 f2bf(float f) {
    union { float f; unsigned int i; } c; c.f = f;
    unsigned int r = c.i + 0x7FFFu + ((c.i >> 16) & 1u);  // RNE
    return (u16)(r >> 16);
}
// async global->LDS, 16B/lane; LDS dest = wave-uniform base + lane*16
__device__ __forceinline__ void async16(const void* g, void* l) {
    __builtin_amdgcn_global_load_lds(
        (const __attribute__((address_space(1))) u32*)g,
        (__attribute__((address_space(3))) u32*)l, 16, 0, 0);
}

// ---------------------------------------------------------------------------
// x f32 -> bf16, 8 elems/thread. N_total = 4,194,304 -> grid 2048 x 256.
// ---------------------------------------------------------------------------
__global__ __launch_bounds__(256) void cast_bf16(
    const float* __restrict__ X, u16* __restrict__ H)
{
    const size_t i = ((size_t)blockIdx.x * 256 + threadIdx.x) * 8;
    u16x8 h;
    #pragma unroll
    for (int e = 0; e < 8; ++e) h[e] = f2bf(X[i + e]);
    *(u16x8*)&H[i] = h;
}

// ---------------------------------------------------------------------------
// Transpose f32 weight W[K][N] -> bf16 Wt [N][K]
// ---------------------------------------------------------------------------
__global__ __launch_bounds__(256) void transpose_cast(
    const float* __restrict__ W, u16* __restrict__ Th, int K, int N)
{
    __shared__ float tile[32][33];
    const int bk = blockIdx.y * 32, bn = blockIdx.x * 32;
    const int tx = threadIdx.x & 31, ty = threadIdx.x >> 5;  // 32 x 8
    #pragma unroll
    for (int r = ty; r < 32; r += 8)
        tile[r][tx] = W[(size_t)(bk + r) * N + bn + tx];
    __syncthreads();
    #pragma unroll
    for (int r = ty; r < 32; r += 8)
        Th[(size_t)(bn + r) * K + bk + tx] = f2bf(tile[tx][r]);
}

// ---------------------------------------------------------------------------
// Single-pass bf16 GEMM: C = A @ B^T + bias (fp32 accum). A bf16 [M][K],
// B pre-transposed bf16 [N][K]. 128x128 tile, BK=32, 4 waves 2x2, 4x4 MFMA.
// m97 structure: global_load_lds width=16 into unpadded [128][32] LDS.
// EPI==0 (QKV): fused per-head RMSNorm -> Qb/Kb bf16 [bh][n][64], and
//               V transpose -> Vt bf16 [bh][d][n].
// EPI==1 (proj): bias + f32 store.
// C/D layout: col = lane&15, row = (lane>>4)*4 + reg (verified m89/m91).
// ---------------------------------------------------------------------------
template <int EPI>
__global__ __launch_bounds__(256) void gemm_fused(
    const u16* __restrict__ AH, const u16* __restrict__ BH,
    const float* __restrict__ bias, float* __restrict__ C,
    u16* __restrict__ Qb, u16* __restrict__ Kb, u16* __restrict__ Vt,
    const float* __restrict__ qw, const float* __restrict__ kw,
    int M, int N, int K)
{
    __shared__ __align__(16) u16 AhT[128 * 32];
    __shared__ __align__(16) u16 BhT[128 * 32];
    const int t = threadIdx.x;
    const int bm = blockIdx.y * 128, bn = blockIdx.x * 128;
    const int wave = t >> 6, lane = t & 63;
    const int wm = (wave >> 1) * 64, wn = (wave & 1) * 64;
    const int l15 = lane & 15, quad = lane >> 4;
    const int srow = lane >> 2, scol = (lane & 3) * 8;  // staging row/col

    f32x4 acc[4][4];
    const f32x4 zero = {0.0f, 0.0f, 0.0f, 0.0f};
    #pragma unroll
    for (int i = 0; i < 4; ++i)
        #pragma unroll
        for (int j = 0; j < 4; ++j) acc[i][j] = zero;

    for (int k0 = 0; k0 < K; k0 += 32) {
        #pragma unroll
        for (int rr = 0; rr < 2; ++rr) {
            const int r0 = (rr * 4 + wave) * 16;   // 16 rows per wave-call
            const size_t ga = (size_t)(bm + r0 + srow) * K + k0 + scol;
            const size_t gb = (size_t)(bn + r0 + srow) * K + k0 + scol;
            async16(&AH[ga], &AhT[r0 * 32]);
            async16(&BH[gb], &BhT[r0 * 32]);
        }
        __syncthreads();   // vmcnt(0) drain + barrier
        bf16x8 ah[4], bh[4];
        #pragma unroll
        for (int i = 0; i < 4; ++i)
            ah[i] = *(const bf16x8*)&AhT[(wm + i * 16 + l15) * 32 + quad * 8];
        #pragma unroll
        for (int j = 0; j < 4; ++j)
            bh[j] = *(const bf16x8*)&BhT[(wn + j * 16 + l15) * 32 + quad * 8];
        #pragma unroll
        for (int i = 0; i < 4; ++i)
            #pragma unroll
            for (int j = 0; j < 4; ++j)
                acc[i][j] = __builtin_amdgcn_mfma_f32_16x16x32_bf16(
                    ah[i], bh[j], acc[i][j], 0, 0, 0);
        __syncthreads();   // frag reads done before next staging overwrite
    }

    if (EPI == 1) {
        #pragma unroll
        for (int j = 0; j < 4; ++j) {
            const int col = bn + wn + j * 16 + l15;
            const float bv = bias[col];
            #pragma unroll
            for (int i = 0; i < 4; ++i) {
                const int row = bm + wm + i * 16 + quad * 4;
                #pragma unroll
                for (int r = 0; r < 4; ++r)
                    C[(size_t)(row + r) * N + col] = acc[i][j][r] + bv;
            }
        }
    } else {
        // wave's 64-col group = one (section, head) pair: gc0 is 64-aligned.
        const int gc0 = bn + wn;
        const int sec = gc0 >> 10;              // 0=q, 1=k, 2=v
        const int h = (gc0 & 1023) >> 6;
        const int b = bm >> 11;                 // uniform: 128-row tile in one b
        const int bhd = b * 16 + h;
        float bv[4], wj[4];
        #pragma unroll
        for (int j = 0; j < 4; ++j) {
            const int d = j * 16 + l15;
            bv[j] = bias[gc0 + d];
            wj[j] = (sec == 2) ? 0.0f : (sec ? kw : qw)[d];
        }
        if (sec < 2) {
            u16* dst = sec ? Kb : Qb;
            #pragma unroll
            for (int i = 0; i < 4; ++i) {
                float val[4][4];   // [j][r]
                float ss[4] = {0.0f, 0.0f, 0.0f, 0.0f};
                #pragma unroll
                for (int j = 0; j < 4; ++j)
                    #pragma unroll
                    for (int r = 0; r < 4; ++r) {
                        val[j][r] = acc[i][j][r] + bv[j];
                        ss[r] += val[j][r] * val[j][r];
                    }
                #pragma unroll
                for (int r = 0; r < 4; ++r) {
                    #pragma unroll
                    for (int m = 1; m < 16; m <<= 1)
                        ss[r] += __shfl_xor(ss[r], m, 64);
                    const float nrm = rsqrtf(ss[r] * 0.015625f + 1e-6f);
                    const int n = (bm + wm + i * 16 + quad * 4 + r) & 2047;
                    const size_t rowb = ((size_t)bhd * 2048 + n) * 64;
                    #pragma unroll
                    for (int j = 0; j < 4; ++j)
                        dst[rowb + j * 16 + l15] = f2bf(val[j][r] * nrm * wj[j]);
                }
            }
        } else {
            #pragma unroll
            for (int i = 0; i < 4; ++i) {
                const int n0 = (bm + wm + i * 16 + quad * 4) & 2047;
                #pragma unroll
                for (int j = 0; j < 4; ++j) {
                    const int d = j * 16 + l15;
                    u16x4 pk;
                    #pragma unroll
                    for (int r = 0; r < 4; ++r)
                        pk[r] = f2bf(acc[i][j][r] + bv[j]);
                    *(u16x4*)&Vt[((size_t)bhd * 64 + d) * 2048 + n0] = pk;
                }
            }
        }
    }
}

// ---------------------------------------------------------------------------
// MFMA flash attention. Block = 4 waves = (bh, 64-row Q tile).
// Static-max softmax (|s| <= 8 by RMSNorm Cauchy-Schwarz).
// Epilogue: single bf16 Attn buffer [B*N][1024].
// ---------------------------------------------------------------------------
__global__ __launch_bounds__(256) void flash_attn_mfma(
    const u16* __restrict__ Qb, const u16* __restrict__ Kb,
    const u16* __restrict__ Vt, u16* __restrict__ Attn)
{
    __shared__ u16 Qlds[64][72];
    __shared__ u16 Klds[64][72];
    __shared__ u16 Vlds[64][72];
    __shared__ u16 Plds[64][80];

    const int t = threadIdx.x;
    const int qt = blockIdx.x;     // 0..31
    const int bh = blockIdx.y;     // 0..31
    const int n0 = qt * 64;
    const size_t qbase = ((size_t)bh * 2048 + n0) * 64;
    const size_t kbase = (size_t)bh * 2048 * 64;
    const size_t vbase = (size_t)bh * 64 * 2048;
    const int wave = t >> 6, lane = t & 63;
    const int l15 = lane & 15, quad = lane >> 4;
    const int sr = t >> 2, seg = (t & 3) * 16;

    *(u16x8*)&Qlds[sr][seg]     = *(const u16x8*)&Qb[qbase + sr * 64 + seg];
    *(u16x8*)&Qlds[sr][seg + 8] = *(const u16x8*)&Qb[qbase + sr * 64 + seg + 8];
    __syncthreads();
    bf16x8 qf0 = *(const bf16x8*)&Qlds[wave * 16 + l15][quad * 8];
    bf16x8 qf1 = *(const bf16x8*)&Qlds[wave * 16 + l15][quad * 8 + 32];

    f32x4 o[4];
    const f32x4 zero = {0.0f, 0.0f, 0.0f, 0.0f};
    #pragma unroll
    for (int dt = 0; dt < 4; ++dt) o[dt] = zero;
    float lsum[4] = {0.0f, 0.0f, 0.0f, 0.0f};
    const float SC = 0.125f * 1.44269504f;

    for (int kt = 0; kt < 32; ++kt) {
        __syncthreads();
        {
            const size_t ko = kbase + (size_t)(kt * 64 + sr) * 64 + seg;
            *(u16x8*)&Klds[sr][seg]     = *(const u16x8*)&Kb[ko];
            *(u16x8*)&Klds[sr][seg + 8] = *(const u16x8*)&Kb[ko + 8];
            const size_t vo = vbase + (size_t)sr * 2048 + kt * 64 + seg;
            *(u16x8*)&Vlds[sr][seg]     = *(const u16x8*)&Vt[vo];
            *(u16x8*)&Vlds[sr][seg + 8] = *(const u16x8*)&Vt[vo + 8];
        }
        __syncthreads();

        f32x4 s[4];
        #pragma unroll
        for (int nt = 0; nt < 4; ++nt) {
            s[nt] = zero;
            bf16x8 kf0 = *(const bf16x8*)&Klds[nt * 16 + l15][quad * 8];
            bf16x8 kf1 = *(const bf16x8*)&Klds[nt * 16 + l15][quad * 8 + 32];
            s[nt] = __builtin_amdgcn_mfma_f32_16x16x32_bf16(qf0, kf0, s[nt], 0, 0, 0);
            s[nt] = __builtin_amdgcn_mfma_f32_16x16x32_bf16(qf1, kf1, s[nt], 0, 0, 0);
        }

        float p[4][4];
        #pragma unroll
        for (int nt = 0; nt < 4; ++nt)
            #pragma unroll
            for (int r = 0; r < 4; ++r)
                p[nt][r] = exp2f(s[nt][r] * SC);
        #pragma unroll
        for (int r = 0; r < 4; ++r)
            lsum[r] += (p[0][r] + p[1][r]) + (p[2][r] + p[3][r]);

        #pragma unroll
        for (int nt = 0; nt < 4; ++nt)
            #pragma unroll
            for (int r = 0; r < 4; ++r)
                Plds[wave * 16 + quad * 4 + r][nt * 16 + l15] = f2bf(p[nt][r]);

        bf16x8 pf0 = *(const bf16x8*)&Plds[wave * 16 + l15][quad * 8];
        bf16x8 pf1 = *(const bf16x8*)&Plds[wave * 16 + l15][quad * 8 + 32];

        #pragma unroll
        for (int dt = 0; dt < 4; ++dt) {
            bf16x8 vf0 = *(const bf16x8*)&Vlds[dt * 16 + l15][quad * 8];
            bf16x8 vf1 = *(const bf16x8*)&Vlds[dt * 16 + l15][quad * 8 + 32];
            o[dt] = __builtin_amdgcn_mfma_f32_16x16x32_bf16(pf0, vf0, o[dt], 0, 0, 0);
            o[dt] = __builtin_amdgcn_mfma_f32_16x16x32_bf16(pf1, vf1, o[dt], 0, 0, 0);
        }
    }

    #pragma unroll
    for (int r = 0; r < 4; ++r) {
        #pragma unroll
        for (int m = 1; m < 16; m <<= 1) lsum[r] += __shfl_xor(lsum[r], m, 64);
    }
    const size_t obase =
        ((size_t)(bh >> 4) * 2048 + n0) * 1024 + (bh & 15) * 64;
    #pragma unroll
    for (int r = 0; r < 4; ++r) {
        const float inv = 1.0f / lsum[r];
        const size_t rbase = obase + (size_t)(wave * 16 + quad * 4 + r) * 1024;
        #pragma unroll
        for (int dt = 0; dt < 4; ++dt)
            Attn[rbase + dt * 16 + l15] = f2bf(o[dt][r] * inv);
    }
}

// ---------------------------------------------------------------------------
extern "C" void kernel_launch(void* const* d_in, const int* in_sizes, int n_in,
                              void* d_out, int out_size, void* d_ws, size_t ws_size,
                              hipStream_t stream)
{
    const float* x      = (const float*)d_in[0];  // [2,2048,1024] f32
    const float* qkv_w  = (const float*)d_in[1];  // [1024,3072]
    const float* qkv_b  = (const float*)d_in[2];  // [3072]
    const float* q_nw   = (const float*)d_in[3];  // [64]
    const float* k_nw   = (const float*)d_in[4];  // [64]
    const float* proj_w = (const float*)d_in[5];  // [1024,1024]
    const float* proj_b = (const float*)d_in[6];  // [1024]
    float* out = (float*)d_out;                   // [2,2048,1024] f32

    // ws layout (48 MB):
    //  [0,8M)    Attn bf16
    //  [8,14M)   qwT bf16     [14,16M) pwT bf16
    //  [16,24M)  Xb bf16
    //  [24,32M)  Qb bf16      [32,40M) Kb bf16   [40,48M) Vt bf16
    char* ws = (char*)d_ws;
    u16* AttnB = (u16*)ws;
    u16* qwT   = (u16*)(ws + 8388608);
    u16* pwT   = (u16*)(ws + 14680064);
    u16* Xb    = (u16*)(ws + 16777216);
    u16* QbB   = (u16*)(ws + 25165824);
    u16* KbB   = (u16*)(ws + 33554432);
    u16* VtB   = (u16*)(ws + 41943040);
    (void)in_sizes; (void)n_in; (void)out_size;
    // Diagnostic guard: if ws too small, emit nothing -> absmax == max|ref|.
    if (ws_size < 50331648u) return;

    // 4,194,304 elems / (256 thr * 8 elems) = 2048 blocks (R5 bug: was 4096)
    cast_bf16<<<dim3(2048), 256, 0, stream>>>(x, Xb);
    transpose_cast<<<dim3(3072 / 32, 1024 / 32), 256, 0, stream>>>(
        qkv_w, qwT, 1024, 3072);
    transpose_cast<<<dim3(1024 / 32, 1024 / 32), 256, 0, stream>>>(
        proj_w, pwT, 1024, 1024);
    // QKV GEMM with fused bias + RMSNorm + head-split/transpose epilogue
    gemm_fused<0><<<dim3(3072 / 128, 4096 / 128), 256, 0, stream>>>(
        Xb, qwT, qkv_b, nullptr, QbB, KbB, VtB, q_nw, k_nw, 4096, 3072, 1024);
    // flash attention -> Attn bf16
    flash_attn_mfma<<<dim3(32, 32), 256, 0, stream>>>(QbB, KbB, VtB, AttnB);
    // out = attn @ proj_w + proj_b (f32)
    gemm_fused<1><<<dim3(1024 / 128, 4096 / 128), 256, 0, stream>>>(
        AttnB, pwT, proj_b, out, nullptr, nullptr, nullptr, nullptr, nullptr,
        4096, 1024, 1024);
}

// Round 7
// 239.595 us; speedup vs baseline: 3.6650x; 1.0427x over previous
//
#include <hip/hip_runtime.h>

typedef unsigned short u16;
typedef unsigned int u32;
typedef __bf16 bf16x8 __attribute__((ext_vector_type(8)));
typedef float f32x4 __attribute__((ext_vector_type(4)));
typedef unsigned short u16x8 __attribute__((ext_vector_type(8)));
typedef unsigned short u16x4 __attribute__((ext_vector_type(4)));
typedef float f4 __attribute__((ext_vector_type(4)));

__device__ __forceinline__ float bf2f(u16 u) {
    union { unsigned int i; float f; } c; c.i = ((unsigned int)u) << 16; return c.f;
}
__device__ __forceinline__ u16 f2bf(float f) {
    union { float f; unsigned int i; } c; c.f = f;
    unsigned int r = c.i + 0x7FFFu + ((c.i >> 16) & 1u);  // RNE
    return (u16)(r >> 16);
}
__device__ __forceinline__ u16 f2bf_rtz(float f) {   // truncate: 1 VALU op
    union { float f; unsigned int i; } c; c.f = f;
    return (u16)(c.i >> 16);
}
__device__ __forceinline__ float fast_exp2(float x) {
#if __has_builtin(__builtin_amdgcn_exp2f)
    return __builtin_amdgcn_exp2f(x);   // raw v_exp_f32, no OCML fixup
#else
    return exp2f(x);
#endif
}
// async global->LDS, 16B/lane; LDS dest = wave-uniform base + lane*16
__device__ __forceinline__ void async16(const void* g, void* l) {
    __builtin_amdgcn_global_load_lds(
        (const __attribute__((address_space(1))) u32*)g,
        (__attribute__((address_space(3))) u32*)l, 16, 0, 0);
}

// ---------------------------------------------------------------------------
// x f32 -> bf16, 8 elems/thread. 4,194,304 elems -> grid 2048 x 256.
// ---------------------------------------------------------------------------
__global__ __launch_bounds__(256) void cast_bf16(
    const float* __restrict__ X, u16* __restrict__ H)
{
    const size_t i = ((size_t)blockIdx.x * 256 + threadIdx.x) * 8;
    u16x8 h;
    #pragma unroll
    for (int e = 0; e < 8; ++e) h[e] = f2bf(X[i + e]);
    *(u16x8*)&H[i] = h;
}

// ---------------------------------------------------------------------------
// Transpose f32 weight W[K][N] -> bf16 Wt [N][K]
// ---------------------------------------------------------------------------
__global__ __launch_bounds__(256) void transpose_cast(
    const float* __restrict__ W, u16* __restrict__ Th, int K, int N)
{
    __shared__ float tile[32][33];
    const int bk = blockIdx.y * 32, bn = blockIdx.x * 32;
    const int tx = threadIdx.x & 31, ty = threadIdx.x >> 5;  // 32 x 8
    #pragma unroll
    for (int r = ty; r < 32; r += 8)
        tile[r][tx] = W[(size_t)(bk + r) * N + bn + tx];
    __syncthreads();
    #pragma unroll
    for (int r = ty; r < 32; r += 8)
        Th[(size_t)(bn + r) * K + bk + tx] = f2bf(tile[tx][r]);
}

// ---------------------------------------------------------------------------
// Single-pass bf16 GEMM: C = A @ B^T + bias (fp32 accum). A bf16 [M][K],
// B pre-transposed bf16 [N][K]. 128x128 tile, BK=32, 4 waves 2x2, 4x4 MFMA.
// m97 structure: global_load_lds width=16 into unpadded [128][32] LDS.
// EPI==0 (QKV): fused per-head RMSNorm -> Qb/Kb bf16 [bh][n][64] (q gets
//               the softmax scale 1/8*log2e folded in), V transpose -> Vt.
// EPI==1 (proj): bias + f32 store.
// C/D layout: col = lane&15, row = (lane>>4)*4 + reg (verified m89/m91).
// ---------------------------------------------------------------------------
template <int EPI>
__global__ __launch_bounds__(256) void gemm_fused(
    const u16* __restrict__ AH, const u16* __restrict__ BH,
    const float* __restrict__ bias, float* __restrict__ C,
    u16* __restrict__ Qb, u16* __restrict__ Kb, u16* __restrict__ Vt,
    const float* __restrict__ qw, const float* __restrict__ kw,
    int M, int N, int K)
{
    __shared__ __align__(16) u16 AhT[128 * 32];
    __shared__ __align__(16) u16 BhT[128 * 32];
    const int t = threadIdx.x;
    const int bm = blockIdx.y * 128, bn = blockIdx.x * 128;
    const int wave = t >> 6, lane = t & 63;
    const int wm = (wave >> 1) * 64, wn = (wave & 1) * 64;
    const int l15 = lane & 15, quad = lane >> 4;
    const int srow = lane >> 2, scol = (lane & 3) * 8;  // staging row/col

    f32x4 acc[4][4];
    const f32x4 zero = {0.0f, 0.0f, 0.0f, 0.0f};
    #pragma unroll
    for (int i = 0; i < 4; ++i)
        #pragma unroll
        for (int j = 0; j < 4; ++j) acc[i][j] = zero;

    for (int k0 = 0; k0 < K; k0 += 32) {
        #pragma unroll
        for (int rr = 0; rr < 2; ++rr) {
            const int r0 = (rr * 4 + wave) * 16;   // 16 rows per wave-call
            const size_t ga = (size_t)(bm + r0 + srow) * K + k0 + scol;
            const size_t gb = (size_t)(bn + r0 + srow) * K + k0 + scol;
            async16(&AH[ga], &AhT[r0 * 32]);
            async16(&BH[gb], &BhT[r0 * 32]);
        }
        __syncthreads();   // vmcnt(0) drain + barrier
        bf16x8 ah[4], bh[4];
        #pragma unroll
        for (int i = 0; i < 4; ++i)
            ah[i] = *(const bf16x8*)&AhT[(wm + i * 16 + l15) * 32 + quad * 8];
        #pragma unroll
        for (int j = 0; j < 4; ++j)
            bh[j] = *(const bf16x8*)&BhT[(wn + j * 16 + l15) * 32 + quad * 8];
        #pragma unroll
        for (int i = 0; i < 4; ++i)
            #pragma unroll
            for (int j = 0; j < 4; ++j)
                acc[i][j] = __builtin_amdgcn_mfma_f32_16x16x32_bf16(
                    ah[i], bh[j], acc[i][j], 0, 0, 0);
        __syncthreads();   // frag reads done before next staging overwrite
    }

    if (EPI == 1) {
        #pragma unroll
        for (int j = 0; j < 4; ++j) {
            const int col = bn + wn + j * 16 + l15;
            const float bv = bias[col];
            #pragma unroll
            for (int i = 0; i < 4; ++i) {
                const int row = bm + wm + i * 16 + quad * 4;
                #pragma unroll
                for (int r = 0; r < 4; ++r)
                    C[(size_t)(row + r) * N + col] = acc[i][j][r] + bv;
            }
        }
    } else {
        // wave's 64-col group = one (section, head) pair: gc0 is 64-aligned.
        const int gc0 = bn + wn;
        const int sec = gc0 >> 10;              // 0=q, 1=k, 2=v
        const int h = (gc0 & 1023) >> 6;
        const int b = bm >> 11;                 // uniform: 128-row tile in one b
        const int bhd = b * 16 + h;
        float bv[4], wj[4];
        #pragma unroll
        for (int j = 0; j < 4; ++j) {
            const int d = j * 16 + l15;
            bv[j] = bias[gc0 + d];
            // q gets 1/sqrt(64)*log2(e) folded in: flash exp2 takes s raw
            wj[j] = (sec == 2) ? 0.0f
                  : (sec ? kw[d] : qw[d] * 0.18033688011f);
        }
        if (sec < 2) {
            u16* dst = sec ? Kb : Qb;
            #pragma unroll
            for (int i = 0; i < 4; ++i) {
                float val[4][4];   // [j][r]
                float ss[4] = {0.0f, 0.0f, 0.0f, 0.0f};
                #pragma unroll
                for (int j = 0; j < 4; ++j)
                    #pragma unroll
                    for (int r = 0; r < 4; ++r) {
                        val[j][r] = acc[i][j][r] + bv[j];
                        ss[r] += val[j][r] * val[j][r];
                    }
                #pragma unroll
                for (int r = 0; r < 4; ++r) {
                    #pragma unroll
                    for (int m = 1; m < 16; m <<= 1)
                        ss[r] += __shfl_xor(ss[r], m, 64);
                    const float nrm = rsqrtf(ss[r] * 0.015625f + 1e-6f);
                    const int n = (bm + wm + i * 16 + quad * 4 + r) & 2047;
                    const size_t rowb = ((size_t)bhd * 2048 + n) * 64;
                    #pragma unroll
                    for (int j = 0; j < 4; ++j)
                        dst[rowb + j * 16 + l15] = f2bf(val[j][r] * nrm * wj[j]);
                }
            }
        } else {
            #pragma unroll
            for (int i = 0; i < 4; ++i) {
                const int n0 = (bm + wm + i * 16 + quad * 4) & 2047;
                #pragma unroll
                for (int j = 0; j < 4; ++j) {
                    const int d = j * 16 + l15;
                    u16x4 pk;
                    #pragma unroll
                    for (int r = 0; r < 4; ++r)
                        pk[r] = f2bf(acc[i][j][r] + bv[j]);
                    *(u16x4*)&Vt[((size_t)bhd * 64 + d) * 2048 + n0] = pk;
                }
            }
        }
    }
}

// ---------------------------------------------------------------------------
// MFMA flash attention. Block = 4 waves = (bh, 64-row Q tile).
// Static-max softmax: Qb pre-scaled so p = exp2(s) directly; |s| <= 11.6
// (RMSNorm Cauchy-Schwarz bound) so raw v_exp_f32 is safe, no overflow.
// P round-trip: RTZ bf16 stores into Plds stride-72 rows (2-way banks, free),
// b128 A-layout reads (144B row stride = 16B aligned).
// ---------------------------------------------------------------------------
__global__ __launch_bounds__(256) void flash_attn_mfma(
    const u16* __restrict__ Qb, const u16* __restrict__ Kb,
    const u16* __restrict__ Vt, u16* __restrict__ Attn)
{
    __shared__ u16 Qlds[64][72];
    __shared__ u16 Klds[64][72];
    __shared__ u16 Vlds[64][72];
    __shared__ u16 Plds[64][72];

    const int t = threadIdx.x;
    const int qt = blockIdx.x;     // 0..31
    const int bh = blockIdx.y;     // 0..31
    const int n0 = qt * 64;
    const size_t qbase = ((size_t)bh * 2048 + n0) * 64;
    const size_t kbase = (size_t)bh * 2048 * 64;
    const size_t vbase = (size_t)bh * 64 * 2048;
    const int wave = t >> 6, lane = t & 63;
    const int l15 = lane & 15, quad = lane >> 4;
    const int sr = t >> 2, seg = (t & 3) * 16;

    *(u16x8*)&Qlds[sr][seg]     = *(const u16x8*)&Qb[qbase + sr * 64 + seg];
    *(u16x8*)&Qlds[sr][seg + 8] = *(const u16x8*)&Qb[qbase + sr * 64 + seg + 8];
    __syncthreads();
    bf16x8 qf0 = *(const bf16x8*)&Qlds[wave * 16 + l15][quad * 8];
    bf16x8 qf1 = *(const bf16x8*)&Qlds[wave * 16 + l15][quad * 8 + 32];

    f32x4 o[4];
    const f32x4 zero = {0.0f, 0.0f, 0.0f, 0.0f};
    #pragma unroll
    for (int dt = 0; dt < 4; ++dt) o[dt] = zero;
    float lsum[4] = {0.0f, 0.0f, 0.0f, 0.0f};

    for (int kt = 0; kt < 32; ++kt) {
        __syncthreads();
        {
            const size_t ko = kbase + (size_t)(kt * 64 + sr) * 64 + seg;
            *(u16x8*)&Klds[sr][seg]     = *(const u16x8*)&Kb[ko];
            *(u16x8*)&Klds[sr][seg + 8] = *(const u16x8*)&Kb[ko + 8];
            const size_t vo = vbase + (size_t)sr * 2048 + kt * 64 + seg;
            *(u16x8*)&Vlds[sr][seg]     = *(const u16x8*)&Vt[vo];
            *(u16x8*)&Vlds[sr][seg + 8] = *(const u16x8*)&Vt[vo + 8];
        }
        __syncthreads();

        f32x4 s[4];
        #pragma unroll
        for (int nt = 0; nt < 4; ++nt) {
            s[nt] = zero;
            bf16x8 kf0 = *(const bf16x8*)&Klds[nt * 16 + l15][quad * 8];
            bf16x8 kf1 = *(const bf16x8*)&Klds[nt * 16 + l15][quad * 8 + 32];
            s[nt] = __builtin_amdgcn_mfma_f32_16x16x32_bf16(qf0, kf0, s[nt], 0, 0, 0);
            s[nt] = __builtin_amdgcn_mfma_f32_16x16x32_bf16(qf1, kf1, s[nt], 0, 0, 0);
        }

        float p[4][4];
        #pragma unroll
        for (int nt = 0; nt < 4; ++nt)
            #pragma unroll
            for (int r = 0; r < 4; ++r)
                p[nt][r] = fast_exp2(s[nt][r]);   // scale pre-folded into Qb
        #pragma unroll
        for (int r = 0; r < 4; ++r)
            lsum[r] += (p[0][r] + p[1][r]) + (p[2][r] + p[3][r]);

        #pragma unroll
        for (int nt = 0; nt < 4; ++nt)
            #pragma unroll
            for (int r = 0; r < 4; ++r)
                Plds[wave * 16 + quad * 4 + r][nt * 16 + l15] =
                    f2bf_rtz(p[nt][r]);

        bf16x8 pf0 = *(const bf16x8*)&Plds[wave * 16 + l15][quad * 8];
        bf16x8 pf1 = *(const bf16x8*)&Plds[wave * 16 + l15][quad * 8 + 32];

        #pragma unroll
        for (int dt = 0; dt < 4; ++dt) {
            bf16x8 vf0 = *(const bf16x8*)&Vlds[dt * 16 + l15][quad * 8];
            bf16x8 vf1 = *(const bf16x8*)&Vlds[dt * 16 + l15][quad * 8 + 32];
            o[dt] = __builtin_amdgcn_mfma_f32_16x16x32_bf16(pf0, vf0, o[dt], 0, 0, 0);
            o[dt] = __builtin_amdgcn_mfma_f32_16x16x32_bf16(pf1, vf1, o[dt], 0, 0, 0);
        }
    }

    #pragma unroll
    for (int r = 0; r < 4; ++r) {
        #pragma unroll
        for (int m = 1; m < 16; m <<= 1) lsum[r] += __shfl_xor(lsum[r], m, 64);
    }
    const size_t obase =
        ((size_t)(bh >> 4) * 2048 + n0) * 1024 + (bh & 15) * 64;
    #pragma unroll
    for (int r = 0; r < 4; ++r) {
        const float inv = 1.0f / lsum[r];
        const size_t rbase = obase + (size_t)(wave * 16 + quad * 4 + r) * 1024;
        #pragma unroll
        for (int dt = 0; dt < 4; ++dt)
            Attn[rbase + dt * 16 + l15] = f2bf(o[dt][r] * inv);
    }
}

// ---------------------------------------------------------------------------
extern "C" void kernel_launch(void* const* d_in, const int* in_sizes, int n_in,
                              void* d_out, int out_size, void* d_ws, size_t ws_size,
                              hipStream_t stream)
{
    const float* x      = (const float*)d_in[0];  // [2,2048,1024] f32
    const float* qkv_w  = (const float*)d_in[1];  // [1024,3072]
    const float* qkv_b  = (const float*)d_in[2];  // [3072]
    const float* q_nw   = (const float*)d_in[3];  // [64]
    const float* k_nw   = (const float*)d_in[4];  // [64]
    const float* proj_w = (const float*)d_in[5];  // [1024,1024]
    const float* proj_b = (const float*)d_in[6];  // [1024]
    float* out = (float*)d_out;                   // [2,2048,1024] f32

    // ws layout (48 MB):
    //  [0,8M)    Attn bf16
    //  [8,14M)   qwT bf16     [14,16M) pwT bf16
    //  [16,24M)  Xb bf16
    //  [24,32M)  Qb bf16      [32,40M) Kb bf16   [40,48M) Vt bf16
    char* ws = (char*)d_ws;
    u16* AttnB = (u16*)ws;
    u16* qwT   = (u16*)(ws + 8388608);
    u16* pwT   = (u16*)(ws + 14680064);
    u16* Xb    = (u16*)(ws + 16777216);
    u16* QbB   = (u16*)(ws + 25165824);
    u16* KbB   = (u16*)(ws + 33554432);
    u16* VtB   = (u16*)(ws + 41943040);
    (void)in_sizes; (void)n_in; (void)out_size;
    // Diagnostic guard: if ws too small, emit nothing -> absmax == max|ref|.
    if (ws_size < 50331648u) return;

    cast_bf16<<<dim3(2048), 256, 0, stream>>>(x, Xb);
    transpose_cast<<<dim3(3072 / 32, 1024 / 32), 256, 0, stream>>>(
        qkv_w, qwT, 1024, 3072);
    transpose_cast<<<dim3(1024 / 32, 1024 / 32), 256, 0, stream>>>(
        proj_w, pwT, 1024, 1024);
    // QKV GEMM with fused bias + RMSNorm + head-split/transpose epilogue
    gemm_fused<0><<<dim3(3072 / 128, 4096 / 128), 256, 0, stream>>>(
        Xb, qwT, qkv_b, nullptr, QbB, KbB, VtB, q_nw, k_nw, 4096, 3072, 1024);
    // flash attention -> Attn bf16
    flash_attn_mfma<<<dim3(32, 32), 256, 0, stream>>>(QbB, KbB, VtB, AttnB);
    // out = attn @ proj_w + proj_b (f32)
    gemm_fused<1><<<dim3(1024 / 128, 4096 / 128), 256, 0, stream>>>(
        AttnB, pwT, proj_b, out, nullptr, nullptr, nullptr, nullptr, nullptr,
        4096, 1024, 1024);
}

// Round 8
// 226.240 us; speedup vs baseline: 3.8814x; 1.0590x over previous
//
#include <hip/hip_runtime.h>

typedef unsigned short u16;
typedef unsigned int u32;
typedef __bf16 bf16x8 __attribute__((ext_vector_type(8)));
typedef float f32x4 __attribute__((ext_vector_type(4)));
typedef unsigned short u16x8 __attribute__((ext_vector_type(8)));
typedef unsigned short u16x4 __attribute__((ext_vector_type(4)));
typedef float f4 __attribute__((ext_vector_type(4)));

__device__ __forceinline__ float bf2f(u16 u) {
    union { unsigned int i; float f; } c; c.i = ((unsigned int)u) << 16; return c.f;
}
__device__ __forceinline__ u16 f2bf(float f) {
    union { float f; unsigned int i; } c; c.f = f;
    unsigned int r = c.i + 0x7FFFu + ((c.i >> 16) & 1u);  // RNE
    return (u16)(r >> 16);
}
__device__ __forceinline__ u16 f2bf_rtz(float f) {   // truncate: 1 VALU op
    union { float f; unsigned int i; } c; c.f = f;
    return (u16)(c.i >> 16);
}
__device__ __forceinline__ float fast_exp2(float x) {
#if __has_builtin(__builtin_amdgcn_exp2f)
    return __builtin_amdgcn_exp2f(x);   // raw v_exp_f32, no OCML fixup
#else
    return exp2f(x);
#endif
}
// async global->LDS, 16B/lane; LDS dest = wave-uniform base + lane*16
__device__ __forceinline__ void async16(const void* g, void* l) {
    __builtin_amdgcn_global_load_lds(
        (const __attribute__((address_space(1))) u32*)g,
        (__attribute__((address_space(3))) u32*)l, 16, 0, 0);
}

// ---------------------------------------------------------------------------
// x f32 -> bf16, 8 elems/thread. 4,194,304 elems -> grid 2048 x 256.
// ---------------------------------------------------------------------------
__global__ __launch_bounds__(256) void cast_bf16(
    const float* __restrict__ X, u16* __restrict__ H)
{
    const size_t i = ((size_t)blockIdx.x * 256 + threadIdx.x) * 8;
    u16x8 h;
    #pragma unroll
    for (int e = 0; e < 8; ++e) h[e] = f2bf(X[i + e]);
    *(u16x8*)&H[i] = h;
}

// ---------------------------------------------------------------------------
// Transpose f32 weight W[K][N] -> bf16 Wt [N][K]
// ---------------------------------------------------------------------------
__global__ __launch_bounds__(256) void transpose_cast(
    const float* __restrict__ W, u16* __restrict__ Th, int K, int N)
{
    __shared__ float tile[32][33];
    const int bk = blockIdx.y * 32, bn = blockIdx.x * 32;
    const int tx = threadIdx.x & 31, ty = threadIdx.x >> 5;  // 32 x 8
    #pragma unroll
    for (int r = ty; r < 32; r += 8)
        tile[r][tx] = W[(size_t)(bk + r) * N + bn + tx];
    __syncthreads();
    #pragma unroll
    for (int r = ty; r < 32; r += 8)
        Th[(size_t)(bn + r) * K + bk + tx] = f2bf(tile[tx][r]);
}

// ---------------------------------------------------------------------------
// Single-pass bf16 GEMM: C = A @ B^T + bias (fp32 accum). A bf16 [M][K],
// B pre-transposed bf16 [N][K]. 128x128 tile, BK=32, 4 waves 2x2, 4x4 MFMA.
// m97 structure: global_load_lds width=16 into unpadded [128][32] LDS.
// EPI==0 (QKV): fused per-head RMSNorm -> Qb/Kb bf16 [bh][n][64] (q gets
//               the softmax scale 1/8*log2e folded in), V transpose -> Vt.
// EPI==1 (proj): bias + f32 store.
// C/D layout: col = lane&15, row = (lane>>4)*4 + reg (verified m89/m91).
// ---------------------------------------------------------------------------
template <int EPI>
__global__ __launch_bounds__(256) void gemm_fused(
    const u16* __restrict__ AH, const u16* __restrict__ BH,
    const float* __restrict__ bias, float* __restrict__ C,
    u16* __restrict__ Qb, u16* __restrict__ Kb, u16* __restrict__ Vt,
    const float* __restrict__ qw, const float* __restrict__ kw,
    int M, int N, int K)
{
    __shared__ __align__(16) u16 AhT[128 * 32];
    __shared__ __align__(16) u16 BhT[128 * 32];
    const int t = threadIdx.x;
    const int bm = blockIdx.y * 128, bn = blockIdx.x * 128;
    const int wave = t >> 6, lane = t & 63;
    const int wm = (wave >> 1) * 64, wn = (wave & 1) * 64;
    const int l15 = lane & 15, quad = lane >> 4;
    const int srow = lane >> 2, scol = (lane & 3) * 8;  // staging row/col

    f32x4 acc[4][4];
    const f32x4 zero = {0.0f, 0.0f, 0.0f, 0.0f};
    #pragma unroll
    for (int i = 0; i < 4; ++i)
        #pragma unroll
        for (int j = 0; j < 4; ++j) acc[i][j] = zero;

    for (int k0 = 0; k0 < K; k0 += 32) {
        #pragma unroll
        for (int rr = 0; rr < 2; ++rr) {
            const int r0 = (rr * 4 + wave) * 16;   // 16 rows per wave-call
            const size_t ga = (size_t)(bm + r0 + srow) * K + k0 + scol;
            const size_t gb = (size_t)(bn + r0 + srow) * K + k0 + scol;
            async16(&AH[ga], &AhT[r0 * 32]);
            async16(&BH[gb], &BhT[r0 * 32]);
        }
        __syncthreads();   // vmcnt(0) drain + barrier
        bf16x8 ah[4], bh[4];
        #pragma unroll
        for (int i = 0; i < 4; ++i)
            ah[i] = *(const bf16x8*)&AhT[(wm + i * 16 + l15) * 32 + quad * 8];
        #pragma unroll
        for (int j = 0; j < 4; ++j)
            bh[j] = *(const bf16x8*)&BhT[(wn + j * 16 + l15) * 32 + quad * 8];
        #pragma unroll
        for (int i = 0; i < 4; ++i)
            #pragma unroll
            for (int j = 0; j < 4; ++j)
                acc[i][j] = __builtin_amdgcn_mfma_f32_16x16x32_bf16(
                    ah[i], bh[j], acc[i][j], 0, 0, 0);
        __syncthreads();   // frag reads done before next staging overwrite
    }

    if (EPI == 1) {
        #pragma unroll
        for (int j = 0; j < 4; ++j) {
            const int col = bn + wn + j * 16 + l15;
            const float bv = bias[col];
            #pragma unroll
            for (int i = 0; i < 4; ++i) {
                const int row = bm + wm + i * 16 + quad * 4;
                #pragma unroll
                for (int r = 0; r < 4; ++r)
                    C[(size_t)(row + r) * N + col] = acc[i][j][r] + bv;
            }
        }
    } else {
        // wave's 64-col group = one (section, head) pair: gc0 is 64-aligned.
        const int gc0 = bn + wn;
        const int sec = gc0 >> 10;              // 0=q, 1=k, 2=v
        const int h = (gc0 & 1023) >> 6;
        const int b = bm >> 11;                 // uniform: 128-row tile in one b
        const int bhd = b * 16 + h;
        float bv[4], wj[4];
        #pragma unroll
        for (int j = 0; j < 4; ++j) {
            const int d = j * 16 + l15;
            bv[j] = bias[gc0 + d];
            // q gets 1/sqrt(64)*log2(e) folded in: flash exp2 takes s raw
            wj[j] = (sec == 2) ? 0.0f
                  : (sec ? kw[d] : qw[d] * 0.18033688011f);
        }
        if (sec < 2) {
            u16* dst = sec ? Kb : Qb;
            #pragma unroll
            for (int i = 0; i < 4; ++i) {
                float val[4][4];   // [j][r]
                float ss[4] = {0.0f, 0.0f, 0.0f, 0.0f};
                #pragma unroll
                for (int j = 0; j < 4; ++j)
                    #pragma unroll
                    for (int r = 0; r < 4; ++r) {
                        val[j][r] = acc[i][j][r] + bv[j];
                        ss[r] += val[j][r] * val[j][r];
                    }
                #pragma unroll
                for (int r = 0; r < 4; ++r) {
                    #pragma unroll
                    for (int m = 1; m < 16; m <<= 1)
                        ss[r] += __shfl_xor(ss[r], m, 64);
                    const float nrm = rsqrtf(ss[r] * 0.015625f + 1e-6f);
                    const int n = (bm + wm + i * 16 + quad * 4 + r) & 2047;
                    const size_t rowb = ((size_t)bhd * 2048 + n) * 64;
                    #pragma unroll
                    for (int j = 0; j < 4; ++j)
                        dst[rowb + j * 16 + l15] = f2bf(val[j][r] * nrm * wj[j]);
                }
            }
        } else {
            #pragma unroll
            for (int i = 0; i < 4; ++i) {
                const int n0 = (bm + wm + i * 16 + quad * 4) & 2047;
                #pragma unroll
                for (int j = 0; j < 4; ++j) {
                    const int d = j * 16 + l15;
                    u16x4 pk;
                    #pragma unroll
                    for (int r = 0; r < 4; ++r)
                        pk[r] = f2bf(acc[i][j][r] + bv[j]);
                    *(u16x4*)&Vt[((size_t)bhd * 64 + d) * 2048 + n0] = pk;
                }
            }
        }
    }
}

// ---------------------------------------------------------------------------
// MFMA flash attention v2. Block = 4 waves = (bh, 128-row Q tile); each wave
// owns 32 q rows (2 A-frag pairs) so K/V frag reads amortize over 2x MFMA.
// Q/K/V staged via global_load_lds (DMA) into XOR-swizzled unpadded [.][64]
// u16 rows: logical 16B colgroup g of row r stored at position g^(r&7) ->
// DMA writes contiguous, frag reads 2-way banks (free). Frag addresses are
// loop-invariant (precomputed). Static-max softmax: Qb pre-scaled so
// p = exp2(s) raw (|s| <= 11.6, no overflow). P round-trip via padded LDS.
// ---------------------------------------------------------------------------
__global__ __launch_bounds__(256) void flash_attn_mfma(
    const u16* __restrict__ Qb, const u16* __restrict__ Kb,
    const u16* __restrict__ Vt, u16* __restrict__ Attn)
{
    __shared__ __align__(16) u16 Qlds[128 * 64];   // swizzled
    __shared__ __align__(16) u16 Klds[64 * 64];    // swizzled [key][d]
    __shared__ __align__(16) u16 Vlds[64 * 64];    // swizzled [d][key]
    __shared__ u16 Plds[128][72];                  // padded, scalar writes

    const int t = threadIdx.x;
    const int qt = blockIdx.x;     // 0..15 (128-row Q tiles)
    const int bh = blockIdx.y;     // 0..31
    const int n0 = qt * 128;
    const size_t qbase = ((size_t)bh * 2048 + n0) * 64;
    const size_t kbase = (size_t)bh * 2048 * 64;
    const size_t vbase = (size_t)bh * 64 * 2048;
    const int wave = t >> 6, lane = t & 63;
    const int l15 = lane & 15, quad = lane >> 4;
    const int srow8 = lane >> 3;   // DMA: row within 8-row call group
    const int sgrp = lane & 7;     // DMA: stored colgroup position

    // stage Q (128 rows, 16 DMA calls, 4 per wave), swizzled
    #pragma unroll
    for (int c = 0; c < 4; ++c) {
        const int r0 = wave * 32 + c * 8;
        const int row = r0 + srow8;
        const int gg = sgrp ^ (row & 7);          // logical group to fetch
        async16(&Qb[qbase + (size_t)row * 64 + gg * 8], &Qlds[r0 * 64]);
    }
    __syncthreads();   // vmcnt drain + barrier

    // loop-invariant frag offsets (u16 units)
    int kofs[4][2];
    #pragma unroll
    for (int nt = 0; nt < 4; ++nt) {
        const int row = nt * 16 + l15;
        kofs[nt][0] = row * 64 + ((quad ^ (row & 7)) * 8);
        kofs[nt][1] = row * 64 + (((quad + 4) ^ (row & 7)) * 8);
    }
    bf16x8 qf[2][2];
    #pragma unroll
    for (int qs = 0; qs < 2; ++qs) {
        const int row = wave * 32 + qs * 16 + l15;
        qf[qs][0] = *(const bf16x8*)&Qlds[row * 64 + ((quad ^ (row & 7)) * 8)];
        qf[qs][1] = *(const bf16x8*)&Qlds[row * 64 + (((quad + 4) ^ (row & 7)) * 8)];
    }

    f32x4 o[2][4];
    const f32x4 zero = {0.0f, 0.0f, 0.0f, 0.0f};
    #pragma unroll
    for (int qs = 0; qs < 2; ++qs)
        #pragma unroll
        for (int dt = 0; dt < 4; ++dt) o[qs][dt] = zero;
    float lsum[2][4] = {};

    for (int kt = 0; kt < 32; ++kt) {
        __syncthreads();   // prior iter frag reads done before DMA overwrite
        // stage K and V tiles: 8 DMA calls each, 2+2 per wave, swizzled
        #pragma unroll
        for (int cc = 0; cc < 2; ++cc) {
            const int r0 = (wave + cc * 4) * 8;
            const int row = r0 + srow8;
            const int gg = sgrp ^ (row & 7);
            async16(&Kb[kbase + (size_t)(kt * 64 + row) * 64 + gg * 8],
                    &Klds[r0 * 64]);
            async16(&Vt[vbase + (size_t)row * 2048 + kt * 64 + gg * 8],
                    &Vlds[r0 * 64]);
        }
        __syncthreads();   // vmcnt drain: K/V visible

        // S = Q K^T : 2 qsub x 4 key-tiles x 2 ksteps
        f32x4 s[2][4];
        #pragma unroll
        for (int nt = 0; nt < 4; ++nt) {
            bf16x8 kf0 = *(const bf16x8*)&Klds[kofs[nt][0]];
            bf16x8 kf1 = *(const bf16x8*)&Klds[kofs[nt][1]];
            #pragma unroll
            for (int qs = 0; qs < 2; ++qs) {
                s[qs][nt] = zero;
                s[qs][nt] = __builtin_amdgcn_mfma_f32_16x16x32_bf16(
                    qf[qs][0], kf0, s[qs][nt], 0, 0, 0);
                s[qs][nt] = __builtin_amdgcn_mfma_f32_16x16x32_bf16(
                    qf[qs][1], kf1, s[qs][nt], 0, 0, 0);
            }
        }

        // p = exp2(s); per-lane partial row sums; P -> LDS (RTZ bf16)
        #pragma unroll
        for (int qs = 0; qs < 2; ++qs) {
            const int prow = wave * 32 + qs * 16 + quad * 4;
            #pragma unroll
            for (int nt = 0; nt < 4; ++nt)
                #pragma unroll
                for (int r = 0; r < 4; ++r) {
                    const float p = fast_exp2(s[qs][nt][r]);
                    lsum[qs][r] += p;
                    Plds[prow + r][nt * 16 + l15] = f2bf_rtz(p);
                }
        }

        // read P back in A-layout (in-wave DS order guarantees visibility)
        bf16x8 pf[2][2];
        #pragma unroll
        for (int qs = 0; qs < 2; ++qs) {
            const int prow = wave * 32 + qs * 16 + l15;
            pf[qs][0] = *(const bf16x8*)&Plds[prow][quad * 8];
            pf[qs][1] = *(const bf16x8*)&Plds[prow][quad * 8 + 32];
        }

        // O += P V : 2 qsub x 4 d-tiles x 2 ksteps
        #pragma unroll
        for (int dt = 0; dt < 4; ++dt) {
            bf16x8 vf0 = *(const bf16x8*)&Vlds[kofs[dt][0]];
            bf16x8 vf1 = *(const bf16x8*)&Vlds[kofs[dt][1]];
            #pragma unroll
            for (int qs = 0; qs < 2; ++qs) {
                o[qs][dt] = __builtin_amdgcn_mfma_f32_16x16x32_bf16(
                    pf[qs][0], vf0, o[qs][dt], 0, 0, 0);
                o[qs][dt] = __builtin_amdgcn_mfma_f32_16x16x32_bf16(
                    pf[qs][1], vf1, o[qs][dt], 0, 0, 0);
            }
        }
    }

    // final l reduction across the 16 key-slices (lanes differing in l15)
    #pragma unroll
    for (int qs = 0; qs < 2; ++qs)
        #pragma unroll
        for (int r = 0; r < 4; ++r) {
            #pragma unroll
            for (int m = 1; m < 16; m <<= 1)
                lsum[qs][r] += __shfl_xor(lsum[qs][r], m, 64);
        }
    const size_t obase =
        ((size_t)(bh >> 4) * 2048 + n0) * 1024 + (bh & 15) * 64;
    #pragma unroll
    for (int qs = 0; qs < 2; ++qs)
        #pragma unroll
        for (int r = 0; r < 4; ++r) {
            const float inv = 1.0f / lsum[qs][r];
            const size_t rbase =
                obase + (size_t)(wave * 32 + qs * 16 + quad * 4 + r) * 1024;
            #pragma unroll
            for (int dt = 0; dt < 4; ++dt)
                Attn[rbase + dt * 16 + l15] = f2bf(o[qs][dt][r] * inv);
        }
}

// ---------------------------------------------------------------------------
extern "C" void kernel_launch(void* const* d_in, const int* in_sizes, int n_in,
                              void* d_out, int out_size, void* d_ws, size_t ws_size,
                              hipStream_t stream)
{
    const float* x      = (const float*)d_in[0];  // [2,2048,1024] f32
    const float* qkv_w  = (const float*)d_in[1];  // [1024,3072]
    const float* qkv_b  = (const float*)d_in[2];  // [3072]
    const float* q_nw   = (const float*)d_in[3];  // [64]
    const float* k_nw   = (const float*)d_in[4];  // [64]
    const float* proj_w = (const float*)d_in[5];  // [1024,1024]
    const float* proj_b = (const float*)d_in[6];  // [1024]
    float* out = (float*)d_out;                   // [2,2048,1024] f32

    // ws layout (48 MB):
    //  [0,8M)    Attn bf16
    //  [8,14M)   qwT bf16     [14,16M) pwT bf16
    //  [16,24M)  Xb bf16
    //  [24,32M)  Qb bf16      [32,40M) Kb bf16   [40,48M) Vt bf16
    char* ws = (char*)d_ws;
    u16* AttnB = (u16*)ws;
    u16* qwT   = (u16*)(ws + 8388608);
    u16* pwT   = (u16*)(ws + 14680064);
    u16* Xb    = (u16*)(ws + 16777216);
    u16* QbB   = (u16*)(ws + 25165824);
    u16* KbB   = (u16*)(ws + 33554432);
    u16* VtB   = (u16*)(ws + 41943040);
    (void)in_sizes; (void)n_in; (void)out_size;
    // Diagnostic guard: if ws too small, emit nothing -> absmax == max|ref|.
    if (ws_size < 50331648u) return;

    cast_bf16<<<dim3(2048), 256, 0, stream>>>(x, Xb);
    transpose_cast<<<dim3(3072 / 32, 1024 / 32), 256, 0, stream>>>(
        qkv_w, qwT, 1024, 3072);
    transpose_cast<<<dim3(1024 / 32, 1024 / 32), 256, 0, stream>>>(
        proj_w, pwT, 1024, 1024);
    // QKV GEMM with fused bias + RMSNorm + head-split/transpose epilogue
    gemm_fused<0><<<dim3(3072 / 128, 4096 / 128), 256, 0, stream>>>(
        Xb, qwT, qkv_b, nullptr, QbB, KbB, VtB, q_nw, k_nw, 4096, 3072, 1024);
    // flash attention v2: 128-row Q tiles
    flash_attn_mfma<<<dim3(16, 32), 256, 0, stream>>>(QbB, KbB, VtB, AttnB);
    // out = attn @ proj_w + proj_b (f32)
    gemm_fused<1><<<dim3(1024 / 128, 4096 / 128), 256, 0, stream>>>(
        AttnB, pwT, proj_b, out, nullptr, nullptr, nullptr, nullptr, nullptr,
        4096, 1024, 1024);
}

// Round 9
// 211.808 us; speedup vs baseline: 4.1458x; 1.0681x over previous
//
#include <hip/hip_runtime.h>

typedef unsigned short u16;
typedef unsigned int u32;
typedef __bf16 bf16x8 __attribute__((ext_vector_type(8)));
typedef float f32x4 __attribute__((ext_vector_type(4)));
typedef unsigned short u16x8 __attribute__((ext_vector_type(8)));
typedef unsigned short u16x4 __attribute__((ext_vector_type(4)));
typedef float f4 __attribute__((ext_vector_type(4)));

__device__ __forceinline__ float bf2f(u16 u) {
    union { unsigned int i; float f; } c; c.i = ((unsigned int)u) << 16; return c.f;
}
__device__ __forceinline__ u16 f2bf(float f) {
    union { float f; unsigned int i; } c; c.f = f;
    unsigned int r = c.i + 0x7FFFu + ((c.i >> 16) & 1u);  // RNE
    return (u16)(r >> 16);
}
__device__ __forceinline__ u16 f2bf_rtz(float f) {   // truncate: 1 VALU op
    union { float f; unsigned int i; } c; c.f = f;
    return (u16)(c.i >> 16);
}
__device__ __forceinline__ float fast_exp2(float x) {
#if __has_builtin(__builtin_amdgcn_exp2f)
    return __builtin_amdgcn_exp2f(x);   // raw v_exp_f32, no OCML fixup
#else
    return exp2f(x);
#endif
}
// async global->LDS, 16B/lane; LDS dest = wave-uniform base + lane*16
__device__ __forceinline__ void async16(const void* g, void* l) {
    __builtin_amdgcn_global_load_lds(
        (const __attribute__((address_space(1))) u32*)g,
        (__attribute__((address_space(3))) u32*)l, 16, 0, 0);
}

// ---------------------------------------------------------------------------
// x f32 -> bf16, 8 elems/thread. 4,194,304 elems -> grid 2048 x 256.
// ---------------------------------------------------------------------------
__global__ __launch_bounds__(256) void cast_bf16(
    const float* __restrict__ X, u16* __restrict__ H)
{
    const size_t i = ((size_t)blockIdx.x * 256 + threadIdx.x) * 8;
    u16x8 h;
    #pragma unroll
    for (int e = 0; e < 8; ++e) h[e] = f2bf(X[i + e]);
    *(u16x8*)&H[i] = h;
}

// ---------------------------------------------------------------------------
// Transpose f32 weight W[K][N] -> bf16 Wt [N][K]
// ---------------------------------------------------------------------------
__global__ __launch_bounds__(256) void transpose_cast(
    const float* __restrict__ W, u16* __restrict__ Th, int K, int N)
{
    __shared__ float tile[32][33];
    const int bk = blockIdx.y * 32, bn = blockIdx.x * 32;
    const int tx = threadIdx.x & 31, ty = threadIdx.x >> 5;  // 32 x 8
    #pragma unroll
    for (int r = ty; r < 32; r += 8)
        tile[r][tx] = W[(size_t)(bk + r) * N + bn + tx];
    __syncthreads();
    #pragma unroll
    for (int r = ty; r < 32; r += 8)
        Th[(size_t)(bn + r) * K + bk + tx] = f2bf(tile[tx][r]);
}

// ---------------------------------------------------------------------------
// QKV GEMM (128x128 tile, BK=32, m97 staging) with fused bias + per-head
// RMSNorm -> Qb/Kb bf16 [bh][n][64] (q gets 1/8*log2e folded in) and
// V transpose -> Vt bf16 [bh][d][n].
// C/D layout: col = lane&15, row = (lane>>4)*4 + reg (verified m89/m91).
// ---------------------------------------------------------------------------
__global__ __launch_bounds__(256) void gemm_qkv(
    const u16* __restrict__ AH, const u16* __restrict__ BH,
    const float* __restrict__ bias,
    u16* __restrict__ Qb, u16* __restrict__ Kb, u16* __restrict__ Vt,
    const float* __restrict__ qw, const float* __restrict__ kw)
{
    const int M = 4096, N = 3072, K = 1024; (void)M; (void)N;
    __shared__ __align__(16) u16 AhT[128 * 32];
    __shared__ __align__(16) u16 BhT[128 * 32];
    const int t = threadIdx.x;
    const int bm = blockIdx.y * 128, bn = blockIdx.x * 128;
    const int wave = t >> 6, lane = t & 63;
    const int wm = (wave >> 1) * 64, wn = (wave & 1) * 64;
    const int l15 = lane & 15, quad = lane >> 4;
    const int srow = lane >> 2, scol = (lane & 3) * 8;

    f32x4 acc[4][4];
    const f32x4 zero = {0.0f, 0.0f, 0.0f, 0.0f};
    #pragma unroll
    for (int i = 0; i < 4; ++i)
        #pragma unroll
        for (int j = 0; j < 4; ++j) acc[i][j] = zero;

    for (int k0 = 0; k0 < K; k0 += 32) {
        #pragma unroll
        for (int rr = 0; rr < 2; ++rr) {
            const int r0 = (rr * 4 + wave) * 16;
            const size_t ga = (size_t)(bm + r0 + srow) * K + k0 + scol;
            const size_t gb = (size_t)(bn + r0 + srow) * K + k0 + scol;
            async16(&AH[ga], &AhT[r0 * 32]);
            async16(&BH[gb], &BhT[r0 * 32]);
        }
        __syncthreads();
        bf16x8 ah[4], bh[4];
        #pragma unroll
        for (int i = 0; i < 4; ++i)
            ah[i] = *(const bf16x8*)&AhT[(wm + i * 16 + l15) * 32 + quad * 8];
        #pragma unroll
        for (int j = 0; j < 4; ++j)
            bh[j] = *(const bf16x8*)&BhT[(wn + j * 16 + l15) * 32 + quad * 8];
        #pragma unroll
        for (int i = 0; i < 4; ++i)
            #pragma unroll
            for (int j = 0; j < 4; ++j)
                acc[i][j] = __builtin_amdgcn_mfma_f32_16x16x32_bf16(
                    ah[i], bh[j], acc[i][j], 0, 0, 0);
        __syncthreads();
    }

    // wave's 64-col group = one (section, head) pair
    const int gc0 = bn + wn;
    const int sec = gc0 >> 10;              // 0=q, 1=k, 2=v
    const int h = (gc0 & 1023) >> 6;
    const int b = bm >> 11;
    const int bhd = b * 16 + h;
    float bv[4], wj[4];
    #pragma unroll
    for (int j = 0; j < 4; ++j) {
        const int d = j * 16 + l15;
        bv[j] = bias[gc0 + d];
        wj[j] = (sec == 2) ? 0.0f : (sec ? kw[d] : qw[d] * 0.18033688011f);
    }
    if (sec < 2) {
        u16* dst = sec ? Kb : Qb;
        #pragma unroll
        for (int i = 0; i < 4; ++i) {
            float val[4][4];
            float ss[4] = {0.0f, 0.0f, 0.0f, 0.0f};
            #pragma unroll
            for (int j = 0; j < 4; ++j)
                #pragma unroll
                for (int r = 0; r < 4; ++r) {
                    val[j][r] = acc[i][j][r] + bv[j];
                    ss[r] += val[j][r] * val[j][r];
                }
            #pragma unroll
            for (int r = 0; r < 4; ++r) {
                #pragma unroll
                for (int m = 1; m < 16; m <<= 1)
                    ss[r] += __shfl_xor(ss[r], m, 64);
                const float nrm = rsqrtf(ss[r] * 0.015625f + 1e-6f);
                const int n = (bm + wm + i * 16 + quad * 4 + r) & 2047;
                const size_t rowb = ((size_t)bhd * 2048 + n) * 64;
                #pragma unroll
                for (int j = 0; j < 4; ++j)
                    dst[rowb + j * 16 + l15] = f2bf(val[j][r] * nrm * wj[j]);
            }
        }
    } else {
        #pragma unroll
        for (int i = 0; i < 4; ++i) {
            const int n0 = (bm + wm + i * 16 + quad * 4) & 2047;
            #pragma unroll
            for (int j = 0; j < 4; ++j) {
                const int d = j * 16 + l15;
                u16x4 pk;
                #pragma unroll
                for (int r = 0; r < 4; ++r)
                    pk[r] = f2bf(acc[i][j][r] + bv[j]);
                *(u16x4*)&Vt[((size_t)bhd * 64 + d) * 2048 + n0] = pk;
            }
        }
    }
}

// ---------------------------------------------------------------------------
// Proj GEMM, 64x128 tile (M x N) for 512-block occupancy (2/CU vs 1/CU at
// 128x128: grid was only 256 blocks). Wave = all 64 rows x 32 cols, acc 4x2.
// out f32 = Attn @ pwT^T + bias.
// ---------------------------------------------------------------------------
__global__ __launch_bounds__(256) void gemm_proj(
    const u16* __restrict__ AH, const u16* __restrict__ BH,
    const float* __restrict__ bias, float* __restrict__ C)
{
    const int N = 1024, K = 1024;
    __shared__ __align__(16) u16 AhT[64 * 32];
    __shared__ __align__(16) u16 BhT[128 * 32];
    const int t = threadIdx.x;
    const int bm = blockIdx.y * 64, bn = blockIdx.x * 128;
    const int wave = t >> 6, lane = t & 63;
    const int l15 = lane & 15, quad = lane >> 4;
    const int srow = lane >> 2, scol = (lane & 3) * 8;

    f32x4 acc[4][2];
    const f32x4 zero = {0.0f, 0.0f, 0.0f, 0.0f};
    #pragma unroll
    for (int i = 0; i < 4; ++i)
        #pragma unroll
        for (int j = 0; j < 2; ++j) acc[i][j] = zero;

    for (int k0 = 0; k0 < K; k0 += 32) {
        {   // A: 64 rows, one 16-row DMA call per wave
            const int r0 = wave * 16;
            async16(&AH[(size_t)(bm + r0 + srow) * K + k0 + scol],
                    &AhT[r0 * 32]);
        }
        #pragma unroll
        for (int cc = 0; cc < 2; ++cc) {   // B: 128 rows, 2 calls per wave
            const int r0 = (wave * 2 + cc) * 16;
            async16(&BH[(size_t)(bn + r0 + srow) * K + k0 + scol],
                    &BhT[r0 * 32]);
        }
        __syncthreads();
        bf16x8 ah[4], bh[2];
        #pragma unroll
        for (int i = 0; i < 4; ++i)
            ah[i] = *(const bf16x8*)&AhT[(i * 16 + l15) * 32 + quad * 8];
        #pragma unroll
        for (int j = 0; j < 2; ++j)
            bh[j] = *(const bf16x8*)
                &BhT[(wave * 32 + j * 16 + l15) * 32 + quad * 8];
        #pragma unroll
        for (int i = 0; i < 4; ++i)
            #pragma unroll
            for (int j = 0; j < 2; ++j)
                acc[i][j] = __builtin_amdgcn_mfma_f32_16x16x32_bf16(
                    ah[i], bh[j], acc[i][j], 0, 0, 0);
        __syncthreads();
    }

    #pragma unroll
    for (int j = 0; j < 2; ++j) {
        const int col = bn + wave * 32 + j * 16 + l15;
        const float bv = bias[col];
        #pragma unroll
        for (int i = 0; i < 4; ++i) {
            const int row = bm + i * 16 + quad * 4;
            #pragma unroll
            for (int r = 0; r < 4; ++r)
                C[(size_t)(row + r) * N + col] = acc[i][j][r] + bv;
        }
    }
}

// ---------------------------------------------------------------------------
// MFMA flash attention v3: K-split x2 over grid.z (static-max softmax =>
// partial O and l over disjoint key ranges are simply additive).
// Block = 4 waves = (bh, 128-row Q tile, 16 k-tiles). Swizzled DMA staging.
// Outputs: Opart f32 [z][4096][1024] (unnormalized), Lpart f32 [z][32][2048].
// ---------------------------------------------------------------------------
__global__ __launch_bounds__(256) void flash_attn_mfma(
    const u16* __restrict__ Qb, const u16* __restrict__ Kb,
    const u16* __restrict__ Vt, float* __restrict__ Opart,
    float* __restrict__ Lpart)
{
    __shared__ __align__(16) u16 Qlds[128 * 64];   // swizzled
    __shared__ __align__(16) u16 Klds[64 * 64];    // swizzled [key][d]
    __shared__ __align__(16) u16 Vlds[64 * 64];    // swizzled [d][key]
    __shared__ u16 Plds[128][72];                  // padded, scalar writes

    const int t = threadIdx.x;
    const int qt = blockIdx.x;     // 0..15 (128-row Q tiles)
    const int bh = blockIdx.y;     // 0..31
    const int z = blockIdx.z;      // 0..1 (k-split half)
    const int n0 = qt * 128;
    const size_t qbase = ((size_t)bh * 2048 + n0) * 64;
    const size_t kbase = (size_t)bh * 2048 * 64;
    const size_t vbase = (size_t)bh * 64 * 2048;
    const int wave = t >> 6, lane = t & 63;
    const int l15 = lane & 15, quad = lane >> 4;
    const int srow8 = lane >> 3;
    const int sgrp = lane & 7;

    // stage Q (128 rows, 16 DMA calls, 4 per wave), swizzled
    #pragma unroll
    for (int c = 0; c < 4; ++c) {
        const int r0 = wave * 32 + c * 8;
        const int row = r0 + srow8;
        const int gg = sgrp ^ (row & 7);
        async16(&Qb[qbase + (size_t)row * 64 + gg * 8], &Qlds[r0 * 64]);
    }
    __syncthreads();

    int kofs[4][2];
    #pragma unroll
    for (int nt = 0; nt < 4; ++nt) {
        const int row = nt * 16 + l15;
        kofs[nt][0] = row * 64 + ((quad ^ (row & 7)) * 8);
        kofs[nt][1] = row * 64 + (((quad + 4) ^ (row & 7)) * 8);
    }
    bf16x8 qf[2][2];
    #pragma unroll
    for (int qs = 0; qs < 2; ++qs) {
        const int row = wave * 32 + qs * 16 + l15;
        qf[qs][0] = *(const bf16x8*)&Qlds[row * 64 + ((quad ^ (row & 7)) * 8)];
        qf[qs][1] = *(const bf16x8*)&Qlds[row * 64 + (((quad + 4) ^ (row & 7)) * 8)];
    }

    f32x4 o[2][4];
    const f32x4 zero = {0.0f, 0.0f, 0.0f, 0.0f};
    #pragma unroll
    for (int qs = 0; qs < 2; ++qs)
        #pragma unroll
        for (int dt = 0; dt < 4; ++dt) o[qs][dt] = zero;
    float lsum[2][4] = {};

    for (int kt = 0; kt < 16; ++kt) {
        const int ktG = z * 16 + kt;
        __syncthreads();
        #pragma unroll
        for (int cc = 0; cc < 2; ++cc) {
            const int r0 = (wave + cc * 4) * 8;
            const int row = r0 + srow8;
            const int gg = sgrp ^ (row & 7);
            async16(&Kb[kbase + (size_t)(ktG * 64 + row) * 64 + gg * 8],
                    &Klds[r0 * 64]);
            async16(&Vt[vbase + (size_t)row * 2048 + ktG * 64 + gg * 8],
                    &Vlds[r0 * 64]);
        }
        __syncthreads();

        f32x4 s[2][4];
        #pragma unroll
        for (int nt = 0; nt < 4; ++nt) {
            bf16x8 kf0 = *(const bf16x8*)&Klds[kofs[nt][0]];
            bf16x8 kf1 = *(const bf16x8*)&Klds[kofs[nt][1]];
            #pragma unroll
            for (int qs = 0; qs < 2; ++qs) {
                s[qs][nt] = zero;
                s[qs][nt] = __builtin_amdgcn_mfma_f32_16x16x32_bf16(
                    qf[qs][0], kf0, s[qs][nt], 0, 0, 0);
                s[qs][nt] = __builtin_amdgcn_mfma_f32_16x16x32_bf16(
                    qf[qs][1], kf1, s[qs][nt], 0, 0, 0);
            }
        }

        #pragma unroll
        for (int qs = 0; qs < 2; ++qs) {
            const int prow = wave * 32 + qs * 16 + quad * 4;
            #pragma unroll
            for (int nt = 0; nt < 4; ++nt)
                #pragma unroll
                for (int r = 0; r < 4; ++r) {
                    const float p = fast_exp2(s[qs][nt][r]);
                    lsum[qs][r] += p;
                    Plds[prow + r][nt * 16 + l15] = f2bf_rtz(p);
                }
        }

        bf16x8 pf[2][2];
        #pragma unroll
        for (int qs = 0; qs < 2; ++qs) {
            const int prow = wave * 32 + qs * 16 + l15;
            pf[qs][0] = *(const bf16x8*)&Plds[prow][quad * 8];
            pf[qs][1] = *(const bf16x8*)&Plds[prow][quad * 8 + 32];
        }

        #pragma unroll
        for (int dt = 0; dt < 4; ++dt) {
            bf16x8 vf0 = *(const bf16x8*)&Vlds[kofs[dt][0]];
            bf16x8 vf1 = *(const bf16x8*)&Vlds[kofs[dt][1]];
            #pragma unroll
            for (int qs = 0; qs < 2; ++qs) {
                o[qs][dt] = __builtin_amdgcn_mfma_f32_16x16x32_bf16(
                    pf[qs][0], vf0, o[qs][dt], 0, 0, 0);
                o[qs][dt] = __builtin_amdgcn_mfma_f32_16x16x32_bf16(
                    pf[qs][1], vf1, o[qs][dt], 0, 0, 0);
            }
        }
    }

    // l reduction across the 16 key-slices (lanes differing in l15)
    #pragma unroll
    for (int qs = 0; qs < 2; ++qs)
        #pragma unroll
        for (int r = 0; r < 4; ++r) {
            #pragma unroll
            for (int m = 1; m < 16; m <<= 1)
                lsum[qs][r] += __shfl_xor(lsum[qs][r], m, 64);
        }
    // store partials (unnormalized O in f32, l per q-row)
    const int b = bh >> 4, h = bh & 15;
    const size_t obase =
        ((size_t)z * 4096 + b * 2048 + n0) * 1024 + h * 64;
    const size_t lbase = (size_t)z * 32 * 2048 + (size_t)bh * 2048 + n0;
    #pragma unroll
    for (int qs = 0; qs < 2; ++qs)
        #pragma unroll
        for (int r = 0; r < 4; ++r) {
            const int rofs = wave * 32 + qs * 16 + quad * 4 + r;
            if (l15 == 0) Lpart[lbase + rofs] = lsum[qs][r];
            const size_t rbase = obase + (size_t)rofs * 1024;
            #pragma unroll
            for (int dt = 0; dt < 4; ++dt)
                Opart[rbase + dt * 16 + l15] = o[qs][dt][r];
        }
}

// ---------------------------------------------------------------------------
// Combine K-split halves: Attn = (O0+O1)/(l0+l1), bf16. One block per row
// (4096), 256 thr x 4 cols. l indexed per (b, h=col/64, n).
// ---------------------------------------------------------------------------
__global__ __launch_bounds__(256) void attn_combine(
    const float* __restrict__ Opart, const float* __restrict__ Lpart,
    u16* __restrict__ Attn)
{
    const int row = blockIdx.x;          // 0..4095 = b*2048+n
    const int t = threadIdx.x;
    const int col = t * 4;
    const int b = row >> 11, n = row & 2047;
    const int h = col >> 6;
    const int bh = b * 16 + h;
    const float l0 = Lpart[(size_t)bh * 2048 + n];
    const float l1 = Lpart[65536 + (size_t)bh * 2048 + n];
    const float inv = 1.0f / (l0 + l1);
    const size_t idx = (size_t)row * 1024 + col;
    f4 o0 = *(const f4*)&Opart[idx];
    f4 o1 = *(const f4*)&Opart[4194304 + idx];
    u16x4 pk;
    #pragma unroll
    for (int e = 0; e < 4; ++e) pk[e] = f2bf((o0[e] + o1[e]) * inv);
    *(u16x4*)&Attn[idx] = pk;
}

// ---------------------------------------------------------------------------
extern "C" void kernel_launch(void* const* d_in, const int* in_sizes, int n_in,
                              void* d_out, int out_size, void* d_ws, size_t ws_size,
                              hipStream_t stream)
{
    const float* x      = (const float*)d_in[0];  // [2,2048,1024] f32
    const float* qkv_w  = (const float*)d_in[1];  // [1024,3072]
    const float* qkv_b  = (const float*)d_in[2];  // [3072]
    const float* q_nw   = (const float*)d_in[3];  // [64]
    const float* k_nw   = (const float*)d_in[4];  // [64]
    const float* proj_w = (const float*)d_in[5];  // [1024,1024]
    const float* proj_b = (const float*)d_in[6];  // [1024]
    float* out = (float*)d_out;                   // [2,2048,1024] f32

    // ws layout (80 MiB):
    //  [0,8M)    Attn bf16
    //  [8,14M)   qwT bf16     [14,16M) pwT bf16
    //  [16,24M)  Xb bf16      (dead after gemm_qkv; Lpart aliases it: 512KB)
    //  [24,32M)  Qb bf16      [32,40M) Kb bf16   [40,48M) Vt bf16
    //  [48,80M)  Opart f32 [2][4096][1024]
    char* ws = (char*)d_ws;
    u16* AttnB  = (u16*)ws;
    u16* qwT    = (u16*)(ws + 8388608);
    u16* pwT    = (u16*)(ws + 14680064);
    u16* Xb     = (u16*)(ws + 16777216);
    float* Lp   = (float*)(ws + 16777216);        // aliases dead Xb
    u16* QbB    = (u16*)(ws + 25165824);
    u16* KbB    = (u16*)(ws + 33554432);
    u16* VtB    = (u16*)(ws + 41943040);
    float* Op   = (float*)(ws + 50331648);
    (void)in_sizes; (void)n_in; (void)out_size;
    // Diagnostic guard: if ws too small, emit nothing -> absmax == max|ref|.
    if (ws_size < 83886080u) return;

    cast_bf16<<<dim3(2048), 256, 0, stream>>>(x, Xb);
    transpose_cast<<<dim3(3072 / 32, 1024 / 32), 256, 0, stream>>>(
        qkv_w, qwT, 1024, 3072);
    transpose_cast<<<dim3(1024 / 32, 1024 / 32), 256, 0, stream>>>(
        proj_w, pwT, 1024, 1024);
    // QKV GEMM with fused bias + RMSNorm + head-split/transpose epilogue
    gemm_qkv<<<dim3(3072 / 128, 4096 / 128), 256, 0, stream>>>(
        Xb, qwT, qkv_b, QbB, KbB, VtB, q_nw, k_nw);
    // flash attention, K-split x2 -> partial O/l
    flash_attn_mfma<<<dim3(16, 32, 2), 256, 0, stream>>>(
        QbB, KbB, VtB, Op, Lp);
    // combine halves -> Attn bf16
    attn_combine<<<dim3(4096), 256, 0, stream>>>(Op, Lp, AttnB);
    // out = attn @ proj_w + proj_b (f32), 64x128 tiles for occupancy
    gemm_proj<<<dim3(1024 / 128, 4096 / 64), 256, 0, stream>>>(
        AttnB, pwT, proj_b, out);
}

// Round 10
// 199.998 us; speedup vs baseline: 4.3906x; 1.0590x over previous
//
#include <hip/hip_runtime.h>

typedef unsigned short u16;
typedef unsigned int u32;
typedef __bf16 bf16x8 __attribute__((ext_vector_type(8)));
typedef float f32x4 __attribute__((ext_vector_type(4)));
typedef unsigned short u16x8 __attribute__((ext_vector_type(8)));
typedef unsigned short u16x4 __attribute__((ext_vector_type(4)));
typedef float f4 __attribute__((ext_vector_type(4)));

__device__ __forceinline__ float bf2f(u16 u) {
    union { unsigned int i; float f; } c; c.i = ((unsigned int)u) << 16; return c.f;
}
__device__ __forceinline__ u16 f2bf(float f) {
    union { float f; unsigned int i; } c; c.f = f;
    unsigned int r = c.i + 0x7FFFu + ((c.i >> 16) & 1u);  // RNE
    return (u16)(r >> 16);
}
__device__ __forceinline__ u16 f2bf_rtz(float f) {   // truncate: 1 VALU op
    union { float f; unsigned int i; } c; c.f = f;
    return (u16)(c.i >> 16);
}
__device__ __forceinline__ float fast_exp2(float x) {
#if __has_builtin(__builtin_amdgcn_exp2f)
    return __builtin_amdgcn_exp2f(x);   // raw v_exp_f32, no OCML fixup
#else
    return exp2f(x);
#endif
}
// async global->LDS, 16B/lane; LDS dest = wave-uniform base + lane*16
__device__ __forceinline__ void async16(const void* g, void* l) {
    __builtin_amdgcn_global_load_lds(
        (const __attribute__((address_space(1))) u32*)g,
        (__attribute__((address_space(3))) u32*)l, 16, 0, 0);
}

// ---------------------------------------------------------------------------
// x f32 -> bf16, 8 elems/thread. 4,194,304 elems -> grid 2048 x 256.
// ---------------------------------------------------------------------------
__global__ __launch_bounds__(256) void cast_bf16(
    const float* __restrict__ X, u16* __restrict__ H)
{
    const size_t i = ((size_t)blockIdx.x * 256 + threadIdx.x) * 8;
    u16x8 h;
    #pragma unroll
    for (int e = 0; e < 8; ++e) h[e] = f2bf(X[i + e]);
    *(u16x8*)&H[i] = h;
}

// ---------------------------------------------------------------------------
// Transpose f32 weight W[K][N] -> bf16 Wt [N][K]
// ---------------------------------------------------------------------------
__global__ __launch_bounds__(256) void transpose_cast(
    const float* __restrict__ W, u16* __restrict__ Th, int K, int N)
{
    __shared__ float tile[32][33];
    const int bk = blockIdx.y * 32, bn = blockIdx.x * 32;
    const int tx = threadIdx.x & 31, ty = threadIdx.x >> 5;  // 32 x 8
    #pragma unroll
    for (int r = ty; r < 32; r += 8)
        tile[r][tx] = W[(size_t)(bk + r) * N + bn + tx];
    __syncthreads();
    #pragma unroll
    for (int r = ty; r < 32; r += 8)
        Th[(size_t)(bn + r) * K + bk + tx] = f2bf(tile[tx][r]);
}

// ---------------------------------------------------------------------------
// QKV GEMM (128x128 tile, BK=32, m97 staging) with fused bias + per-head
// RMSNorm -> Qb/Kb bf16 [bh][n][64] (q gets 1/8*log2e folded in) and
// V transpose -> Vt bf16 [bh][d][n].
// C/D layout: col = lane&15, row = (lane>>4)*4 + reg (verified m89/m91).
// ---------------------------------------------------------------------------
__global__ __launch_bounds__(256) void gemm_qkv(
    const u16* __restrict__ AH, const u16* __restrict__ BH,
    const float* __restrict__ bias,
    u16* __restrict__ Qb, u16* __restrict__ Kb, u16* __restrict__ Vt,
    const float* __restrict__ qw, const float* __restrict__ kw)
{
    const int K = 1024;
    __shared__ __align__(16) u16 AhT[128 * 32];
    __shared__ __align__(16) u16 BhT[128 * 32];
    const int t = threadIdx.x;
    const int bm = blockIdx.y * 128, bn = blockIdx.x * 128;
    const int wave = t >> 6, lane = t & 63;
    const int wm = (wave >> 1) * 64, wn = (wave & 1) * 64;
    const int l15 = lane & 15, quad = lane >> 4;
    const int srow = lane >> 2, scol = (lane & 3) * 8;

    f32x4 acc[4][4];
    const f32x4 zero = {0.0f, 0.0f, 0.0f, 0.0f};
    #pragma unroll
    for (int i = 0; i < 4; ++i)
        #pragma unroll
        for (int j = 0; j < 4; ++j) acc[i][j] = zero;

    for (int k0 = 0; k0 < K; k0 += 32) {
        #pragma unroll
        for (int rr = 0; rr < 2; ++rr) {
            const int r0 = (rr * 4 + wave) * 16;
            const size_t ga = (size_t)(bm + r0 + srow) * K + k0 + scol;
            const size_t gb = (size_t)(bn + r0 + srow) * K + k0 + scol;
            async16(&AH[ga], &AhT[r0 * 32]);
            async16(&BH[gb], &BhT[r0 * 32]);
        }
        __syncthreads();
        bf16x8 ah[4], bh[4];
        #pragma unroll
        for (int i = 0; i < 4; ++i)
            ah[i] = *(const bf16x8*)&AhT[(wm + i * 16 + l15) * 32 + quad * 8];
        #pragma unroll
        for (int j = 0; j < 4; ++j)
            bh[j] = *(const bf16x8*)&BhT[(wn + j * 16 + l15) * 32 + quad * 8];
        #pragma unroll
        for (int i = 0; i < 4; ++i)
            #pragma unroll
            for (int j = 0; j < 4; ++j)
                acc[i][j] = __builtin_amdgcn_mfma_f32_16x16x32_bf16(
                    ah[i], bh[j], acc[i][j], 0, 0, 0);
        __syncthreads();
    }

    // wave's 64-col group = one (section, head) pair
    const int gc0 = bn + wn;
    const int sec = gc0 >> 10;              // 0=q, 1=k, 2=v
    const int h = (gc0 & 1023) >> 6;
    const int b = bm >> 11;
    const int bhd = b * 16 + h;
    float bv[4], wj[4];
    #pragma unroll
    for (int j = 0; j < 4; ++j) {
        const int d = j * 16 + l15;
        bv[j] = bias[gc0 + d];
        wj[j] = (sec == 2) ? 0.0f : (sec ? kw[d] : qw[d] * 0.18033688011f);
    }
    if (sec < 2) {
        u16* dst = sec ? Kb : Qb;
        #pragma unroll
        for (int i = 0; i < 4; ++i) {
            float val[4][4];
            float ss[4] = {0.0f, 0.0f, 0.0f, 0.0f};
            #pragma unroll
            for (int j = 0; j < 4; ++j)
                #pragma unroll
                for (int r = 0; r < 4; ++r) {
                    val[j][r] = acc[i][j][r] + bv[j];
                    ss[r] += val[j][r] * val[j][r];
                }
            #pragma unroll
            for (int r = 0; r < 4; ++r) {
                #pragma unroll
                for (int m = 1; m < 16; m <<= 1)
                    ss[r] += __shfl_xor(ss[r], m, 64);
                const float nrm = rsqrtf(ss[r] * 0.015625f + 1e-6f);
                const int n = (bm + wm + i * 16 + quad * 4 + r) & 2047;
                const size_t rowb = ((size_t)bhd * 2048 + n) * 64;
                #pragma unroll
                for (int j = 0; j < 4; ++j)
                    dst[rowb + j * 16 + l15] = f2bf(val[j][r] * nrm * wj[j]);
            }
        }
    } else {
        #pragma unroll
        for (int i = 0; i < 4; ++i) {
            const int n0 = (bm + wm + i * 16 + quad * 4) & 2047;
            #pragma unroll
            for (int j = 0; j < 4; ++j) {
                const int d = j * 16 + l15;
                u16x4 pk;
                #pragma unroll
                for (int r = 0; r < 4; ++r)
                    pk[r] = f2bf(acc[i][j][r] + bv[j]);
                *(u16x4*)&Vt[((size_t)bhd * 64 + d) * 2048 + n0] = pk;
            }
        }
    }
}

// ---------------------------------------------------------------------------
// Proj GEMM, 64x128 tile for 512-block occupancy. Wave = 64 rows x 32 cols.
// out f32 = Attn @ pwT^T + bias.
// ---------------------------------------------------------------------------
__global__ __launch_bounds__(256) void gemm_proj(
    const u16* __restrict__ AH, const u16* __restrict__ BH,
    const float* __restrict__ bias, float* __restrict__ C)
{
    const int N = 1024, K = 1024;
    __shared__ __align__(16) u16 AhT[64 * 32];
    __shared__ __align__(16) u16 BhT[128 * 32];
    const int t = threadIdx.x;
    const int bm = blockIdx.y * 64, bn = blockIdx.x * 128;
    const int wave = t >> 6, lane = t & 63;
    const int l15 = lane & 15, quad = lane >> 4;
    const int srow = lane >> 2, scol = (lane & 3) * 8;

    f32x4 acc[4][2];
    const f32x4 zero = {0.0f, 0.0f, 0.0f, 0.0f};
    #pragma unroll
    for (int i = 0; i < 4; ++i)
        #pragma unroll
        for (int j = 0; j < 2; ++j) acc[i][j] = zero;

    for (int k0 = 0; k0 < K; k0 += 32) {
        {
            const int r0 = wave * 16;
            async16(&AH[(size_t)(bm + r0 + srow) * K + k0 + scol],
                    &AhT[r0 * 32]);
        }
        #pragma unroll
        for (int cc = 0; cc < 2; ++cc) {
            const int r0 = (wave * 2 + cc) * 16;
            async16(&BH[(size_t)(bn + r0 + srow) * K + k0 + scol],
                    &BhT[r0 * 32]);
        }
        __syncthreads();
        bf16x8 ah[4], bh[2];
        #pragma unroll
        for (int i = 0; i < 4; ++i)
            ah[i] = *(const bf16x8*)&AhT[(i * 16 + l15) * 32 + quad * 8];
        #pragma unroll
        for (int j = 0; j < 2; ++j)
            bh[j] = *(const bf16x8*)
                &BhT[(wave * 32 + j * 16 + l15) * 32 + quad * 8];
        #pragma unroll
        for (int i = 0; i < 4; ++i)
            #pragma unroll
            for (int j = 0; j < 2; ++j)
                acc[i][j] = __builtin_amdgcn_mfma_f32_16x16x32_bf16(
                    ah[i], bh[j], acc[i][j], 0, 0, 0);
        __syncthreads();
    }

    #pragma unroll
    for (int j = 0; j < 2; ++j) {
        const int col = bn + wave * 32 + j * 16 + l15;
        const float bv = bias[col];
        #pragma unroll
        for (int i = 0; i < 4; ++i) {
            const int row = bm + i * 16 + quad * 4;
            #pragma unroll
            for (int r = 0; r < 4; ++r)
                C[(size_t)(row + r) * N + col] = acc[i][j][r] + bv;
        }
    }
}

// ---------------------------------------------------------------------------
// MFMA flash attention v4. Block = 4 waves = (bh, 128-row Q tile), full 2048
// keys per block (K-split reverted: measured per-CU-throughput-bound).
// KEY CHANGE vs v2: S^T = K Q^T (operand swap). C/D layout then gives each
// lane P at fixed q=l15, keys=nt*16+quad*4+r -> the 4 r-values are column-
// contiguous in Plds[q][key]: ONE ds_write_b64 each (8 b64 vs 32 b16 before).
// PV unchanged (A=P from Plds b128, B=V) -> O row=q=quad*4+r, col=d=l15.
// lsum: per-lane scalar (q=l15), reduced across quads (xor 16,32) at end,
// broadcast to O-rows via 128-float LDS (in-wave, no barrier).
// ---------------------------------------------------------------------------
__global__ __launch_bounds__(256) void flash_attn_mfma(
    const u16* __restrict__ Qb, const u16* __restrict__ Kb,
    const u16* __restrict__ Vt, u16* __restrict__ Attn)
{
    __shared__ __align__(16) u16 Qlds[128 * 64];   // swizzled
    __shared__ __align__(16) u16 Klds[64 * 64];    // swizzled [key][d]
    __shared__ __align__(16) u16 Vlds[64 * 64];    // swizzled [d][key]
    __shared__ __align__(16) u16 Plds[128][72];    // [q][key], b64 writes
    __shared__ float Lbuf[128];

    const int t = threadIdx.x;
    const int qt = blockIdx.x;     // 0..15 (128-row Q tiles)
    const int bh = blockIdx.y;     // 0..31
    const int n0 = qt * 128;
    const size_t qbase = ((size_t)bh * 2048 + n0) * 64;
    const size_t kbase = (size_t)bh * 2048 * 64;
    const size_t vbase = (size_t)bh * 64 * 2048;
    const int wave = t >> 6, lane = t & 63;
    const int l15 = lane & 15, quad = lane >> 4;
    const int srow8 = lane >> 3;
    const int sgrp = lane & 7;

    // stage Q (128 rows, 16 DMA calls, 4 per wave), swizzled
    #pragma unroll
    for (int c = 0; c < 4; ++c) {
        const int r0 = wave * 32 + c * 8;
        const int row = r0 + srow8;
        const int gg = sgrp ^ (row & 7);
        async16(&Qb[qbase + (size_t)row * 64 + gg * 8], &Qlds[r0 * 64]);
    }
    __syncthreads();

    int kofs[4][2];
    #pragma unroll
    for (int nt = 0; nt < 4; ++nt) {
        const int row = nt * 16 + l15;
        kofs[nt][0] = row * 64 + ((quad ^ (row & 7)) * 8);
        kofs[nt][1] = row * 64 + (((quad + 4) ^ (row & 7)) * 8);
    }
    bf16x8 qf[2][2];
    #pragma unroll
    for (int qs = 0; qs < 2; ++qs) {
        const int row = wave * 32 + qs * 16 + l15;
        qf[qs][0] = *(const bf16x8*)&Qlds[row * 64 + ((quad ^ (row & 7)) * 8)];
        qf[qs][1] = *(const bf16x8*)&Qlds[row * 64 + (((quad + 4) ^ (row & 7)) * 8)];
    }

    f32x4 o[2][4];
    const f32x4 zero = {0.0f, 0.0f, 0.0f, 0.0f};
    #pragma unroll
    for (int qs = 0; qs < 2; ++qs)
        #pragma unroll
        for (int dt = 0; dt < 4; ++dt) o[qs][dt] = zero;
    float lsum[2] = {0.0f, 0.0f};

    for (int kt = 0; kt < 32; ++kt) {
        __syncthreads();   // prior iter frag reads done before DMA overwrite
        #pragma unroll
        for (int cc = 0; cc < 2; ++cc) {
            const int r0 = (wave + cc * 4) * 8;
            const int row = r0 + srow8;
            const int gg = sgrp ^ (row & 7);
            async16(&Kb[kbase + (size_t)(kt * 64 + row) * 64 + gg * 8],
                    &Klds[r0 * 64]);
            async16(&Vt[vbase + (size_t)row * 2048 + kt * 64 + gg * 8],
                    &Vlds[r0 * 64]);
        }
        __syncthreads();   // vmcnt drain: K/V visible

        // S^T = K Q^T : lane gets s[qs][nt][r] = S[q=l15][key=nt*16+quad*4+r]
        f32x4 s[2][4];
        #pragma unroll
        for (int nt = 0; nt < 4; ++nt) {
            bf16x8 kf0 = *(const bf16x8*)&Klds[kofs[nt][0]];
            bf16x8 kf1 = *(const bf16x8*)&Klds[kofs[nt][1]];
            #pragma unroll
            for (int qs = 0; qs < 2; ++qs) {
                s[qs][nt] = zero;
                s[qs][nt] = __builtin_amdgcn_mfma_f32_16x16x32_bf16(
                    kf0, qf[qs][0], s[qs][nt], 0, 0, 0);
                s[qs][nt] = __builtin_amdgcn_mfma_f32_16x16x32_bf16(
                    kf1, qf[qs][1], s[qs][nt], 0, 0, 0);
            }
        }

        // p = exp2(s); lsum += p; pack 4 keys -> one b64 LDS write
        #pragma unroll
        for (int qs = 0; qs < 2; ++qs) {
            const int prow = wave * 32 + qs * 16 + l15;
            #pragma unroll
            for (int nt = 0; nt < 4; ++nt) {
                u16x4 pk;
                #pragma unroll
                for (int r = 0; r < 4; ++r) {
                    const float p = fast_exp2(s[qs][nt][r]);
                    lsum[qs] += p;
                    pk[r] = f2bf_rtz(p);
                }
                *(u16x4*)&Plds[prow][nt * 16 + quad * 4] = pk;
            }
        }

        // read P back in A-layout (in-wave DS order guarantees visibility)
        bf16x8 pf[2][2];
        #pragma unroll
        for (int qs = 0; qs < 2; ++qs) {
            const int prow = wave * 32 + qs * 16 + l15;
            pf[qs][0] = *(const bf16x8*)&Plds[prow][quad * 8];
            pf[qs][1] = *(const bf16x8*)&Plds[prow][quad * 8 + 32];
        }

        // O += P V : 2 qsub x 4 d-tiles x 2 ksteps
        #pragma unroll
        for (int dt = 0; dt < 4; ++dt) {
            bf16x8 vf0 = *(const bf16x8*)&Vlds[kofs[dt][0]];
            bf16x8 vf1 = *(const bf16x8*)&Vlds[kofs[dt][1]];
            #pragma unroll
            for (int qs = 0; qs < 2; ++qs) {
                o[qs][dt] = __builtin_amdgcn_mfma_f32_16x16x32_bf16(
                    pf[qs][0], vf0, o[qs][dt], 0, 0, 0);
                o[qs][dt] = __builtin_amdgcn_mfma_f32_16x16x32_bf16(
                    pf[qs][1], vf1, o[qs][dt], 0, 0, 0);
            }
        }
    }

    // lsum currently: per-lane partial for q=l15 over this quad's keys.
    // Reduce across quads (lane = quad*16+l15: xor 16 and 32), broadcast via
    // Lbuf to the O C-layout rows (q = quad*4+r). In-wave, no barrier.
    #pragma unroll
    for (int qs = 0; qs < 2; ++qs) {
        lsum[qs] += __shfl_xor(lsum[qs], 16, 64);
        lsum[qs] += __shfl_xor(lsum[qs], 32, 64);
        if (quad == 0) Lbuf[wave * 32 + qs * 16 + l15] = lsum[qs];
    }
    const size_t obase =
        ((size_t)(bh >> 4) * 2048 + n0) * 1024 + (bh & 15) * 64;
    #pragma unroll
    for (int qs = 0; qs < 2; ++qs)
        #pragma unroll
        for (int r = 0; r < 4; ++r) {
            const float inv =
                1.0f / Lbuf[wave * 32 + qs * 16 + quad * 4 + r];
            const size_t rbase =
                obase + (size_t)(wave * 32 + qs * 16 + quad * 4 + r) * 1024;
            #pragma unroll
            for (int dt = 0; dt < 4; ++dt)
                Attn[rbase + dt * 16 + l15] = f2bf(o[qs][dt][r] * inv);
        }
}

// ---------------------------------------------------------------------------
extern "C" void kernel_launch(void* const* d_in, const int* in_sizes, int n_in,
                              void* d_out, int out_size, void* d_ws, size_t ws_size,
                              hipStream_t stream)
{
    const float* x      = (const float*)d_in[0];  // [2,2048,1024] f32
    const float* qkv_w  = (const float*)d_in[1];  // [1024,3072]
    const float* qkv_b  = (const float*)d_in[2];  // [3072]
    const float* q_nw   = (const float*)d_in[3];  // [64]
    const float* k_nw   = (const float*)d_in[4];  // [64]
    const float* proj_w = (const float*)d_in[5];  // [1024,1024]
    const float* proj_b = (const float*)d_in[6];  // [1024]
    float* out = (float*)d_out;                   // [2,2048,1024] f32

    // ws layout (48 MB):
    //  [0,8M)    Attn bf16
    //  [8,14M)   qwT bf16     [14,16M) pwT bf16
    //  [16,24M)  Xb bf16
    //  [24,32M)  Qb bf16      [32,40M) Kb bf16   [40,48M) Vt bf16
    char* ws = (char*)d_ws;
    u16* AttnB = (u16*)ws;
    u16* qwT   = (u16*)(ws + 8388608);
    u16* pwT   = (u16*)(ws + 14680064);
    u16* Xb    = (u16*)(ws + 16777216);
    u16* QbB   = (u16*)(ws + 25165824);
    u16* KbB   = (u16*)(ws + 33554432);
    u16* VtB   = (u16*)(ws + 41943040);
    (void)in_sizes; (void)n_in; (void)out_size;
    // Diagnostic guard: if ws too small, emit nothing -> absmax == max|ref|.
    if (ws_size < 50331648u) return;

    cast_bf16<<<dim3(2048), 256, 0, stream>>>(x, Xb);
    transpose_cast<<<dim3(3072 / 32, 1024 / 32), 256, 0, stream>>>(
        qkv_w, qwT, 1024, 3072);
    transpose_cast<<<dim3(1024 / 32, 1024 / 32), 256, 0, stream>>>(
        proj_w, pwT, 1024, 1024);
    // QKV GEMM with fused bias + RMSNorm + head-split/transpose epilogue
    gemm_qkv<<<dim3(3072 / 128, 4096 / 128), 256, 0, stream>>>(
        Xb, qwT, qkv_b, QbB, KbB, VtB, q_nw, k_nw);
    // flash attention v4 (operand-swapped S^T, b64 P writes)
    flash_attn_mfma<<<dim3(16, 32), 256, 0, stream>>>(QbB, KbB, VtB, AttnB);
    // out = attn @ proj_w + proj_b (f32), 64x128 tiles
    gemm_proj<<<dim3(1024 / 128, 4096 / 64), 256, 0, stream>>>(
        AttnB, pwT, proj_b, out);
}